// Round 1
// baseline (353.312 us; speedup 1.0000x reference)
//
#include <hip/hip_runtime.h>
#include <stdint.h>

#define B_ 2
#define S_ 2048
#define H_ 16
#define HKV_ 8
#define D_ 128
#define EPS_ 1e-6f
#define SCALE_ 0.08838834764831845f

typedef __attribute__((ext_vector_type(8))) __bf16 bf16x8;
typedef __attribute__((ext_vector_type(4))) float f32x4;

static __device__ __forceinline__ uint16_t f2b(float f) {
  uint32_t u = __builtin_bit_cast(uint32_t, f);
  u += 0x7fffu + ((u >> 16) & 1u);
  return (uint16_t)(u >> 16);
}
static __device__ __forceinline__ float b2f(uint16_t b) {
  uint32_t u = ((uint32_t)b) << 16;
  return __builtin_bit_cast(float, u);
}

// ---------------- cast fp32 -> bf16 (4 elems/thread) ----------------
__global__ void castk(const float* __restrict__ in, uint16_t* __restrict__ out) {
  int i = blockIdx.x * 256 + threadIdx.x;
  float4 f = ((const float4*)in)[i];
  uint2 o;
  o.x = (uint32_t)f2b(f.x) | ((uint32_t)f2b(f.y) << 16);
  o.y = (uint32_t)f2b(f.z) | ((uint32_t)f2b(f.w) << 16);
  ((uint2*)out)[i] = o;
}

// ------------- transpose+cast: W (K x N fp32) -> Wt (N x K bf16) -------------
__global__ void transcast(const float* __restrict__ Wm, uint16_t* __restrict__ Wt,
                          int K, int N) {
  __shared__ float t[32][33];
  int nb = blockIdx.x * 32, kb = blockIdx.y * 32;
  int tx = threadIdx.x & 31, ty = threadIdx.x >> 5;
  #pragma unroll
  for (int i = ty; i < 32; i += 8) t[i][tx] = Wm[(size_t)(kb + i) * N + nb + tx];
  __syncthreads();
  #pragma unroll
  for (int i = ty; i < 32; i += 8) Wt[(size_t)(nb + i) * K + kb + tx] = f2b(t[tx][i]);
}

// ------------- GEMM: C = A(MxK,bf16,rm) * Bt(NxK,bf16,rm)^T -------------
// mode 0: bf16 row-major MxN out; mode 1: bf16 (b, head, s, d) out; mode 2: f32 rm out
__global__ __launch_bounds__(256) void gemm_bt(const uint16_t* __restrict__ A,
                                               const uint16_t* __restrict__ Bt,
                                               void* __restrict__ Cout,
                                               int M, int N, int K, int mode, int NH) {
  __shared__ uint16_t Al[128 * 64];
  __shared__ uint16_t Bl[128 * 64];
  int tid = threadIdx.x;
  int lane = tid & 63, lr = lane & 15, g = lane >> 4;
  int w = tid >> 6, wm = w >> 1, wn = w & 1;
  int m0 = blockIdx.y * 128, n0 = blockIdx.x * 128;
  f32x4 acc[4][4] = {};
  for (int k0 = 0; k0 < K; k0 += 64) {
    __syncthreads();
    #pragma unroll
    for (int p = 0; p < 4; ++p) {
      int c = tid + p * 256;
      int row = c >> 3, cb = c & 7;
      int dst = row * 128 + ((cb * 16) ^ ((row & 7) << 4));
      uint4 va = *(const uint4*)(A + (size_t)(m0 + row) * K + k0 + cb * 8);
      *(uint4*)((char*)Al + dst) = va;
      uint4 vb = *(const uint4*)(Bt + (size_t)(n0 + row) * K + k0 + cb * 8);
      *(uint4*)((char*)Bl + dst) = vb;
    }
    __syncthreads();
    #pragma unroll
    for (int ks = 0; ks < 2; ++ks) {
      bf16x8 af[4], bfr[4];
      #pragma unroll
      for (int mi = 0; mi < 4; ++mi) {
        int row = wm * 64 + mi * 16 + lr;
        af[mi] = *(bf16x8*)((char*)Al + row * 128 + ((ks * 64 + g * 16) ^ ((row & 7) << 4)));
      }
      #pragma unroll
      for (int ni = 0; ni < 4; ++ni) {
        int row = wn * 64 + ni * 16 + lr;
        bfr[ni] = *(bf16x8*)((char*)Bl + row * 128 + ((ks * 64 + g * 16) ^ ((row & 7) << 4)));
      }
      #pragma unroll
      for (int mi = 0; mi < 4; ++mi)
        #pragma unroll
        for (int ni = 0; ni < 4; ++ni)
          acc[mi][ni] = __builtin_amdgcn_mfma_f32_16x16x32_bf16(af[mi], bfr[ni], acc[mi][ni], 0, 0, 0);
    }
  }
  #pragma unroll
  for (int mi = 0; mi < 4; ++mi)
    #pragma unroll
    for (int ni = 0; ni < 4; ++ni)
      #pragma unroll
      for (int e = 0; e < 4; ++e) {
        int row = m0 + wm * 64 + mi * 16 + 4 * g + e;
        int col = n0 + wn * 64 + ni * 16 + lr;
        float v = acc[mi][ni][e];
        if (mode == 2) {
          ((float*)Cout)[(size_t)row * N + col] = v;
        } else if (mode == 0) {
          ((uint16_t*)Cout)[(size_t)row * N + col] = f2b(v);
        } else {
          int bb = row >> 11, s = row & 2047;
          int head = col >> 7, d = col & 127;
          ((uint16_t*)Cout)[(((size_t)(bb * NH + head)) * S_ + s) * D_ + d] = f2b(v);
        }
      }
}

// ------------- RMSNorm + RoPE, in place on Q (b,H,s,d) and K (b,HKV,s,d) -------------
__global__ void norm_rope(uint16_t* __restrict__ Qb, uint16_t* __restrict__ Kb,
                          const float* __restrict__ qw, const float* __restrict__ kw,
                          const float* __restrict__ cosr, const float* __restrict__ sinr) {
  int row = blockIdx.x * 4 + (threadIdx.x >> 6);
  int lane = threadIdx.x & 63;
  int hh = row % 24;
  int bs = row / 24;
  int b = bs >> 11, s = bs & 2047;
  uint16_t* ptr;
  const float* wv;
  if (hh < H_) { ptr = Qb + (((size_t)(b * H_ + hh)) * S_ + s) * D_; wv = qw; }
  else         { ptr = Kb + (((size_t)(b * HKV_ + (hh - H_))) * S_ + s) * D_; wv = kw; }
  float x1 = b2f(ptr[lane]), x2 = b2f(ptr[lane + 64]);
  float ss = x1 * x1 + x2 * x2;
  #pragma unroll
  for (int msk = 1; msk < 64; msk <<= 1) ss += __shfl_xor(ss, msk, 64);
  float r = rsqrtf(ss * (1.0f / 128.0f) + EPS_);
  float n1 = x1 * r * wv[lane], n2 = x2 * r * wv[lane + 64];
  float c1 = cosr[s * 128 + lane], s1 = sinr[s * 128 + lane];
  float c2 = cosr[s * 128 + lane + 64], s2 = sinr[s * 128 + lane + 64];
  ptr[lane]      = f2b(n1 * c1 - n2 * s1);
  ptr[lane + 64] = f2b(n2 * c2 + n1 * s2);
}

// ------------- causal GQA flash attention -------------
// grid: (S/128, B*H). 4 waves, each owns 32 q-rows. KV staged 32 keys at a time.
__global__ __launch_bounds__(256) void attn_kernel(const uint16_t* __restrict__ Qb,
                                                   const uint16_t* __restrict__ Kb,
                                                   const uint16_t* __restrict__ Vb,
                                                   uint16_t* __restrict__ out) {
  __shared__ uint16_t Kl[32 * 128];   // XOR-swizzled rows
  __shared__ uint16_t Vl[32 * 130];   // padded pitch 130 -> conflict-free column reads
  int tid = threadIdx.x, lane = tid & 63, w = tid >> 6, lr = lane & 15, g = lane >> 4;
  int qb = blockIdx.x, bh = blockIdx.y;
  int b = bh >> 4, h = bh & 15, kv = h >> 1;
  const uint16_t* Qg = Qb + ((size_t)(b * H_ + h)) * S_ * D_;
  const uint16_t* Kg = Kb + ((size_t)(b * HKV_ + kv)) * S_ * D_;
  const uint16_t* Vg = Vb + ((size_t)(b * HKV_ + kv)) * S_ * D_;
  int q0 = qb * 128 + w * 32;
  bf16x8 qf[2][4];
  #pragma unroll
  for (int qt = 0; qt < 2; ++qt)
    #pragma unroll
    for (int ks = 0; ks < 4; ++ks)
      qf[qt][ks] = *(const bf16x8*)(Qg + (size_t)(q0 + qt * 16 + lr) * D_ + ks * 32 + g * 8);
  f32x4 O[2][8] = {};
  float m[2] = {-__builtin_inff(), -__builtin_inff()};
  float l[2] = {0.f, 0.f};
  int nkb = qb * 4 + 4;
  for (int kb = 0; kb < nkb; ++kb) {
    __syncthreads();
    #pragma unroll
    for (int p = 0; p < 2; ++p) {
      int c = tid + p * 256;
      int row = c >> 4, cb = c & 15;
      uint4 kd = *(const uint4*)(Kg + (size_t)(kb * 32 + row) * D_ + cb * 8);
      *(uint4*)((char*)Kl + row * 256 + ((cb * 16) ^ ((row & 7) << 4))) = kd;
      uint4 vd = *(const uint4*)(Vg + (size_t)(kb * 32 + row) * D_ + cb * 8);
      uint32_t* vp = (uint32_t*)(Vl + row * 130 + cb * 8);
      vp[0] = vd.x; vp[1] = vd.y; vp[2] = vd.z; vp[3] = vd.w;
    }
    __syncthreads();
    if (kb * 32 > q0 + 31) continue;   // fully-masked for this wave; barriers stay aligned
    // S^T tiles: mfma(A=K_rows, B=Q^T) -> lane holds scores for q = lr, keys t2*16+4g+e
    f32x4 acc[2][2] = {};
    #pragma unroll
    for (int t2 = 0; t2 < 2; ++t2) {
      #pragma unroll
      for (int ks = 0; ks < 4; ++ks) {
        int row = t2 * 16 + lr;
        bf16x8 kf = *(bf16x8*)((char*)Kl + row * 256 + ((ks * 64 + g * 16) ^ ((row & 7) << 4)));
        acc[0][t2] = __builtin_amdgcn_mfma_f32_16x16x32_bf16(kf, qf[0][ks], acc[0][t2], 0, 0, 0);
        acc[1][t2] = __builtin_amdgcn_mfma_f32_16x16x32_bf16(kf, qf[1][ks], acc[1][t2], 0, 0, 0);
      }
    }
    bf16x8 paq[2];
    #pragma unroll
    for (int qt = 0; qt < 2; ++qt) {
      float p[8];
      float mloc = -__builtin_inff();
      int qg = q0 + qt * 16 + lr;
      #pragma unroll
      for (int t2 = 0; t2 < 2; ++t2)
        #pragma unroll
        for (int e = 0; e < 4; ++e) {
          float sc = acc[qt][t2][e] * SCALE_;
          int key = kb * 32 + t2 * 16 + 4 * g + e;
          if (key > qg) sc = -__builtin_inff();
          p[t2 * 4 + e] = sc;
          mloc = fmaxf(mloc, sc);
        }
      mloc = fmaxf(mloc, __shfl_xor(mloc, 16, 64));
      mloc = fmaxf(mloc, __shfl_xor(mloc, 32, 64));
      float mnew = fmaxf(m[qt], mloc);
      float r = __expf(m[qt] - mnew);
      float lloc = 0.f;
      #pragma unroll
      for (int j = 0; j < 8; ++j) { p[j] = __expf(p[j] - mnew); lloc += p[j]; }
      lloc += __shfl_xor(lloc, 16, 64);
      lloc += __shfl_xor(lloc, 32, 64);
      l[qt] = l[qt] * r + lloc;
      m[qt] = mnew;
      #pragma unroll
      for (int e = 0; e < 4; ++e) {
        float rr = __shfl(r, 4 * g + e, 64);
        #pragma unroll
        for (int dt = 0; dt < 8; ++dt) O[qt][dt][e] *= rr;
      }
      // redistribute P (q=lr, key=4g+e layout) into PV A-fragment (q=lr, keys 8g..8g+7)
      union PU { uint16_t s[8]; bf16x8 v; } pu;
      int hi = g >> 1;
      #pragma unroll
      for (int ep = 0; ep < 8; ++ep) {
        int srcL = lr + 16 * (2 * (g & 1) + (ep >> 2));
        float v1 = __shfl(p[ep & 3], srcL, 64);
        float v2 = __shfl(p[4 + (ep & 3)], srcL, 64);
        pu.s[ep] = f2b(hi ? v2 : v1);
      }
      paq[qt] = pu.v;
    }
    #pragma unroll
    for (int dt = 0; dt < 8; ++dt) {
      union VU { uint16_t s[8]; bf16x8 v; } vu;
      #pragma unroll
      for (int ep = 0; ep < 8; ++ep)
        vu.s[ep] = Vl[(8 * g + ep) * 130 + dt * 16 + lr];
      O[0][dt] = __builtin_amdgcn_mfma_f32_16x16x32_bf16(paq[0], vu.v, O[0][dt], 0, 0, 0);
      O[1][dt] = __builtin_amdgcn_mfma_f32_16x16x32_bf16(paq[1], vu.v, O[1][dt], 0, 0, 0);
    }
  }
  #pragma unroll
  for (int qt = 0; qt < 2; ++qt) {
    float linv[4];
    #pragma unroll
    for (int e = 0; e < 4; ++e) linv[e] = 1.0f / __shfl(l[qt], 4 * g + e, 64);
    #pragma unroll
    for (int dt = 0; dt < 8; ++dt)
      #pragma unroll
      for (int e = 0; e < 4; ++e) {
        int qrow = q0 + qt * 16 + 4 * g + e;
        size_t o = ((size_t)(b * S_ + qrow)) * 2048 + h * 128 + dt * 16 + lr;
        out[o] = f2b(O[qt][dt][e] * linv[e]);
      }
  }
}

extern "C" void kernel_launch(void* const* d_in, const int* in_sizes, int n_in,
                              void* d_out, int out_size, void* d_ws, size_t ws_size,
                              hipStream_t stream) {
  const float* hidden = (const float*)d_in[0];
  // d_in[1] = attention_mask (causal tril) -- implied by kernel, not read
  const float* cosr = (const float*)d_in[2];
  const float* sinr = (const float*)d_in[3];
  const float* Wq = (const float*)d_in[4];
  const float* Wk = (const float*)d_in[5];
  const float* Wv = (const float*)d_in[6];
  const float* Wo = (const float*)d_in[7];
  const float* qw = (const float*)d_in[8];
  const float* kw = (const float*)d_in[9];

  uint16_t* p = (uint16_t*)d_ws;
  uint16_t* Xb   = p; p += (size_t)4096 * 1024;
  uint16_t* Wqt  = p; p += (size_t)2048 * 1024;
  uint16_t* Wkt  = p; p += (size_t)1024 * 1024;
  uint16_t* Wvt  = p; p += (size_t)1024 * 1024;
  uint16_t* Wot  = p; p += (size_t)1024 * 2048;
  uint16_t* Qbuf = p; p += (size_t)B_ * H_ * S_ * D_;
  uint16_t* Kbuf = p; p += (size_t)B_ * HKV_ * S_ * D_;
  uint16_t* Vbuf = p; p += (size_t)B_ * HKV_ * S_ * D_;
  uint16_t* attn = p; p += (size_t)4096 * 2048;

  castk<<<4096, 256, 0, stream>>>(hidden, Xb);
  transcast<<<dim3(64, 32), 256, 0, stream>>>(Wq, Wqt, 1024, 2048);
  transcast<<<dim3(32, 32), 256, 0, stream>>>(Wk, Wkt, 1024, 1024);
  transcast<<<dim3(32, 32), 256, 0, stream>>>(Wv, Wvt, 1024, 1024);
  transcast<<<dim3(32, 64), 256, 0, stream>>>(Wo, Wot, 2048, 1024);
  gemm_bt<<<dim3(16, 32), 256, 0, stream>>>(Xb, Wqt, Qbuf, 4096, 2048, 1024, 1, H_);
  gemm_bt<<<dim3(8, 32), 256, 0, stream>>>(Xb, Wkt, Kbuf, 4096, 1024, 1024, 1, HKV_);
  gemm_bt<<<dim3(8, 32), 256, 0, stream>>>(Xb, Wvt, Vbuf, 4096, 1024, 1024, 1, HKV_);
  norm_rope<<<24576, 256, 0, stream>>>(Qbuf, Kbuf, qw, kw, cosr, sinr);
  attn_kernel<<<dim3(16, 32), 256, 0, stream>>>(Qbuf, Kbuf, Vbuf, attn);
  gemm_bt<<<dim3(8, 32), 256, 0, stream>>>(attn, Wot, d_out, 4096, 1024, 2048, 2, 0);
}

// Round 2
// 319.587 us; speedup vs baseline: 1.1055x; 1.1055x over previous
//
#include <hip/hip_runtime.h>
#include <stdint.h>

#define B_ 2
#define S_ 2048
#define H_ 16
#define HKV_ 8
#define D_ 128
#define EPS_ 1e-6f
#define SCALE_ 0.08838834764831845f

typedef __attribute__((ext_vector_type(8))) __bf16 bf16x8;
typedef __attribute__((ext_vector_type(4))) float f32x4;

static __device__ __forceinline__ uint16_t f2b(float f) {
  uint32_t u = __builtin_bit_cast(uint32_t, f);
  u += 0x7fffu + ((u >> 16) & 1u);
  return (uint16_t)(u >> 16);
}
static __device__ __forceinline__ float b2f(uint16_t b) {
  uint32_t u = ((uint32_t)b) << 16;
  return __builtin_bit_cast(float, u);
}

typedef const __attribute__((address_space(1))) uint32_t* gas_p;
typedef __attribute__((address_space(3))) uint32_t* las_p;
static __device__ __forceinline__ void gload16(const void* g, void* l) {
  __builtin_amdgcn_global_load_lds((gas_p)g, (las_p)l, 16, 0, 0);
}

// ---------------- cast fp32 -> bf16 (4 elems/thread) ----------------
__global__ void castk(const float* __restrict__ in, uint16_t* __restrict__ out) {
  int i = blockIdx.x * 256 + threadIdx.x;
  float4 f = ((const float4*)in)[i];
  uint2 o;
  o.x = (uint32_t)f2b(f.x) | ((uint32_t)f2b(f.y) << 16);
  o.y = (uint32_t)f2b(f.z) | ((uint32_t)f2b(f.w) << 16);
  ((uint2*)out)[i] = o;
}

// ------------- transpose+cast: W (K x N fp32) -> Wt (N x K bf16) -------------
__global__ void transcast(const float* __restrict__ Wm, uint16_t* __restrict__ Wt,
                          int K, int N) {
  __shared__ float t[32][33];
  int nb = blockIdx.x * 32, kb = blockIdx.y * 32;
  int tx = threadIdx.x & 31, ty = threadIdx.x >> 5;
  #pragma unroll
  for (int i = ty; i < 32; i += 8) t[i][tx] = Wm[(size_t)(kb + i) * N + nb + tx];
  __syncthreads();
  #pragma unroll
  for (int i = ty; i < 32; i += 8) Wt[(size_t)(nb + i) * K + kb + tx] = f2b(t[tx][i]);
}

// ------------- bf16 transpose: V (bkv, s, 128) -> Vt (bkv, 128, s) -------------
__global__ __launch_bounds__(256) void vtrans(const uint16_t* __restrict__ Vin,
                                              uint16_t* __restrict__ Vt) {
  __shared__ uint16_t L[64 * 64];  // (s, d) tile; 16B chunks XOR-swizzled by s&7
  int s0 = blockIdx.x * 64, d0 = blockIdx.y * 64;
  const uint16_t* src = Vin + (size_t)blockIdx.z * S_ * D_;
  uint16_t* dst = Vt + (size_t)blockIdx.z * S_ * D_;
  int t = threadIdx.x;
  int rr = t >> 3, cb = t & 7;
  #pragma unroll
  for (int half = 0; half < 2; ++half) {
    int row = rr + half * 32;
    uint4 v = *(const uint4*)(src + (size_t)(s0 + row) * D_ + d0 + cb * 8);
    *(uint4*)(L + row * 64 + ((cb ^ (row & 7)) * 8)) = v;
  }
  __syncthreads();
  int dr = t >> 2, sc = (t & 3) * 16;
  union { uint16_t s[16]; uint4 q[2]; } u;
  #pragma unroll
  for (int j = 0; j < 16; ++j) {
    int s = sc + j;
    u.s[j] = L[s * 64 + (((dr >> 3) ^ (s & 7)) * 8) + (dr & 7)];
  }
  uint4* op = (uint4*)(dst + (size_t)(d0 + dr) * S_ + s0 + sc);
  op[0] = u.q[0];
  op[1] = u.q[1];
}

// ------------- GEMM: C = A(MxK,bf16,rm) * Bt(NxK,bf16,rm)^T -------------
// global_load_lds staging: linear LDS dest + inverse-swizzled global source.
// mode 1: bf16 (b, head, s, d) out; mode 2: f32 rm out
__global__ __launch_bounds__(256) void gemm_bt(const uint16_t* __restrict__ A,
                                               const uint16_t* __restrict__ Bt,
                                               void* __restrict__ Cout,
                                               int M, int N, int K, int mode, int NH) {
  __shared__ uint16_t Al[128 * 64];
  __shared__ uint16_t Bl[128 * 64];
  int tid = threadIdx.x;
  int lane = tid & 63, lr = lane & 15, g = lane >> 4;
  int w = tid >> 6, wm = w >> 1, wn = w & 1;
  int wbase = w * 64;  // wave-uniform
  int m0 = blockIdx.y * 128, n0 = blockIdx.x * 128;
  f32x4 acc[4][4] = {};
  for (int k0 = 0; k0 < K; k0 += 64) {
    __syncthreads();
    #pragma unroll
    for (int p = 0; p < 4; ++p) {
      int c = tid + p * 256;
      int row = c >> 3, cb = c & 7;
      int sc = (cb ^ (row & 7)) * 8;  // inverse-swizzled source column (elems)
      gload16(A + (size_t)(m0 + row) * K + k0 + sc, Al + (size_t)(p * 256 + wbase) * 8);
      gload16(Bt + (size_t)(n0 + row) * K + k0 + sc, Bl + (size_t)(p * 256 + wbase) * 8);
    }
    __syncthreads();
    #pragma unroll
    for (int ks = 0; ks < 2; ++ks) {
      bf16x8 af[4], bfr[4];
      #pragma unroll
      for (int mi = 0; mi < 4; ++mi) {
        int row = wm * 64 + mi * 16 + lr;
        af[mi] = *(bf16x8*)((char*)Al + row * 128 + ((ks * 64 + g * 16) ^ ((row & 7) << 4)));
      }
      #pragma unroll
      for (int ni = 0; ni < 4; ++ni) {
        int row = wn * 64 + ni * 16 + lr;
        bfr[ni] = *(bf16x8*)((char*)Bl + row * 128 + ((ks * 64 + g * 16) ^ ((row & 7) << 4)));
      }
      __builtin_amdgcn_s_setprio(1);
      #pragma unroll
      for (int mi = 0; mi < 4; ++mi)
        #pragma unroll
        for (int ni = 0; ni < 4; ++ni)
          acc[mi][ni] = __builtin_amdgcn_mfma_f32_16x16x32_bf16(af[mi], bfr[ni], acc[mi][ni], 0, 0, 0);
      __builtin_amdgcn_s_setprio(0);
    }
  }
  #pragma unroll
  for (int mi = 0; mi < 4; ++mi)
    #pragma unroll
    for (int ni = 0; ni < 4; ++ni)
      #pragma unroll
      for (int e = 0; e < 4; ++e) {
        int row = m0 + wm * 64 + mi * 16 + 4 * g + e;
        int col = n0 + wn * 64 + ni * 16 + lr;
        float v = acc[mi][ni][e];
        if (mode == 2) {
          ((float*)Cout)[(size_t)row * N + col] = v;
        } else {
          int bb = row >> 11, s = row & 2047;
          int head = col >> 7, d = col & 127;
          ((uint16_t*)Cout)[(((size_t)(bb * NH + head)) * S_ + s) * D_ + d] = f2b(v);
        }
      }
}

// ------------- RMSNorm + RoPE, in place on Q (b,H,s,d) and K (b,HKV,s,d) -------------
__global__ void norm_rope(uint16_t* __restrict__ Qb, uint16_t* __restrict__ Kb,
                          const float* __restrict__ qw, const float* __restrict__ kw,
                          const float* __restrict__ cosr, const float* __restrict__ sinr) {
  int row = blockIdx.x * 4 + (threadIdx.x >> 6);
  int lane = threadIdx.x & 63;
  int hh = row % 24;
  int bs = row / 24;
  int b = bs >> 11, s = bs & 2047;
  uint16_t* ptr;
  const float* wv;
  if (hh < H_) { ptr = Qb + (((size_t)(b * H_ + hh)) * S_ + s) * D_; wv = qw; }
  else         { ptr = Kb + (((size_t)(b * HKV_ + (hh - H_))) * S_ + s) * D_; wv = kw; }
  float x1 = b2f(ptr[lane]), x2 = b2f(ptr[lane + 64]);
  float ss = x1 * x1 + x2 * x2;
  #pragma unroll
  for (int msk = 1; msk < 64; msk <<= 1) ss += __shfl_xor(ss, msk, 64);
  float r = rsqrtf(ss * (1.0f / 128.0f) + EPS_);
  float n1 = x1 * r * wv[lane], n2 = x2 * r * wv[lane + 64];
  float c1 = cosr[s * 128 + lane], s1 = sinr[s * 128 + lane];
  float c2 = cosr[s * 128 + lane + 64], s2 = sinr[s * 128 + lane + 64];
  ptr[lane]      = f2b(n1 * c1 - n2 * s1);
  ptr[lane + 64] = f2b(n2 * c2 + n1 * s2);
}

// ------------- causal GQA flash attention: 1 wave / 32 q-rows, no LDS, no barriers ---
// grid 2048 x 64thr. K frags + V^T frags read direct from global (L2-resident).
__global__ __launch_bounds__(64) void attn_kernel(const uint16_t* __restrict__ Qb,
                                                  const uint16_t* __restrict__ Kb,
                                                  const uint16_t* __restrict__ Vtg,
                                                  uint16_t* __restrict__ out) {
  int lane = threadIdx.x & 63, lr = lane & 15, g = lane >> 4;
  // block -> (qt, b, kv, h): XCD-pinned (b,kv), longest q-tiles first
  int wid = blockIdx.x;
  int x = wid & 7, rest = wid >> 3;
  int gsel = rest & 1, hsel = (rest >> 1) & 1, qidx = rest >> 2;
  int gkv = gsel * 8 + x;
  int b = gkv >> 3, kv = gkv & 7, h = kv * 2 + hsel;
  int qt = 63 - qidx;
  const uint16_t* Qg = Qb + ((size_t)(b * H_ + h)) * S_ * D_;
  const uint16_t* Kg = Kb + ((size_t)(b * HKV_ + kv)) * S_ * D_;
  const uint16_t* Vg = Vtg + ((size_t)(b * HKV_ + kv)) * S_ * D_;  // [128][2048]
  int q0 = qt * 32;
  bf16x8 qf[2][4];
  #pragma unroll
  for (int qt2 = 0; qt2 < 2; ++qt2)
    #pragma unroll
    for (int ks = 0; ks < 4; ++ks)
      qf[qt2][ks] = *(const bf16x8*)(Qg + (size_t)(q0 + qt2 * 16 + lr) * D_ + ks * 32 + g * 8);
  f32x4 O[2][8] = {};
  float m[2] = {-__builtin_inff(), -__builtin_inff()};
  float l[2] = {0.f, 0.f};
  for (int kb = 0; kb <= qt; ++kb) {
    // V^T fragments for this 32-key block (independent of softmax -> issued early)
    bf16x8 vf[8];
    #pragma unroll
    for (int dt = 0; dt < 8; ++dt)
      vf[dt] = *(const bf16x8*)(Vg + (size_t)(dt * 16 + lr) * S_ + kb * 32 + 8 * g);
    // S^T tiles: mfma(A=K_rows, B=Q^T) -> lane holds scores for q = lr, keys t2*16+4g+e
    f32x4 acc[2][2] = {};
    #pragma unroll
    for (int t2 = 0; t2 < 2; ++t2) {
      bf16x8 kf[4];
      #pragma unroll
      for (int ks = 0; ks < 4; ++ks)
        kf[ks] = *(const bf16x8*)(Kg + (size_t)(kb * 32 + t2 * 16 + lr) * D_ + ks * 32 + g * 8);
      __builtin_amdgcn_s_setprio(1);
      #pragma unroll
      for (int ks = 0; ks < 4; ++ks) {
        acc[0][t2] = __builtin_amdgcn_mfma_f32_16x16x32_bf16(kf[ks], qf[0][ks], acc[0][t2], 0, 0, 0);
        acc[1][t2] = __builtin_amdgcn_mfma_f32_16x16x32_bf16(kf[ks], qf[1][ks], acc[1][t2], 0, 0, 0);
      }
      __builtin_amdgcn_s_setprio(0);
    }
    bf16x8 paq[2];
    #pragma unroll
    for (int qt2 = 0; qt2 < 2; ++qt2) {
      float p[8];
      float mloc = -__builtin_inff();
      int qg = q0 + qt2 * 16 + lr;
      #pragma unroll
      for (int t2 = 0; t2 < 2; ++t2)
        #pragma unroll
        for (int e = 0; e < 4; ++e) {
          float sc = acc[qt2][t2][e] * SCALE_;
          int key = kb * 32 + t2 * 16 + 4 * g + e;
          if (key > qg) sc = -__builtin_inff();
          p[t2 * 4 + e] = sc;
          mloc = fmaxf(mloc, sc);
        }
      mloc = fmaxf(mloc, __shfl_xor(mloc, 16, 64));
      mloc = fmaxf(mloc, __shfl_xor(mloc, 32, 64));
      float mnew = fmaxf(m[qt2], mloc);
      float r = __expf(m[qt2] - mnew);
      float lloc = 0.f;
      #pragma unroll
      for (int j = 0; j < 8; ++j) { p[j] = __expf(p[j] - mnew); lloc += p[j]; }
      lloc += __shfl_xor(lloc, 16, 64);
      lloc += __shfl_xor(lloc, 32, 64);
      l[qt2] = l[qt2] * r + lloc;
      m[qt2] = mnew;
      #pragma unroll
      for (int e = 0; e < 4; ++e) {
        float rr = __shfl(r, 4 * g + e, 64);
        #pragma unroll
        for (int dt = 0; dt < 8; ++dt) O[qt2][dt][e] *= rr;
      }
      // redistribute P (q=lr, key=4g+e layout) into PV A-fragment (q=lr, keys 8g..8g+7)
      union PU { uint16_t s[8]; bf16x8 v; } pu;
      int hi = g >> 1;
      #pragma unroll
      for (int ep = 0; ep < 8; ++ep) {
        int srcL = lr + 16 * (2 * (g & 1) + (ep >> 2));
        float v1 = __shfl(p[ep & 3], srcL, 64);
        float v2 = __shfl(p[4 + (ep & 3)], srcL, 64);
        pu.s[ep] = f2b(hi ? v2 : v1);
      }
      paq[qt2] = pu.v;
    }
    __builtin_amdgcn_s_setprio(1);
    #pragma unroll
    for (int dt = 0; dt < 8; ++dt) {
      O[0][dt] = __builtin_amdgcn_mfma_f32_16x16x32_bf16(paq[0], vf[dt], O[0][dt], 0, 0, 0);
      O[1][dt] = __builtin_amdgcn_mfma_f32_16x16x32_bf16(paq[1], vf[dt], O[1][dt], 0, 0, 0);
    }
    __builtin_amdgcn_s_setprio(0);
  }
  #pragma unroll
  for (int qt2 = 0; qt2 < 2; ++qt2) {
    float linv[4];
    #pragma unroll
    for (int e = 0; e < 4; ++e) linv[e] = 1.0f / __shfl(l[qt2], 4 * g + e, 64);
    #pragma unroll
    for (int dt = 0; dt < 8; ++dt)
      #pragma unroll
      for (int e = 0; e < 4; ++e) {
        int qrow = q0 + qt2 * 16 + 4 * g + e;
        size_t o = ((size_t)(b * S_ + qrow)) * 2048 + h * 128 + dt * 16 + lr;
        out[o] = f2b(O[qt2][dt][e] * linv[e]);
      }
  }
}

extern "C" void kernel_launch(void* const* d_in, const int* in_sizes, int n_in,
                              void* d_out, int out_size, void* d_ws, size_t ws_size,
                              hipStream_t stream) {
  const float* hidden = (const float*)d_in[0];
  const float* cosr = (const float*)d_in[2];
  const float* sinr = (const float*)d_in[3];
  const float* Wq = (const float*)d_in[4];
  const float* Wk = (const float*)d_in[5];
  const float* Wv = (const float*)d_in[6];
  const float* Wo = (const float*)d_in[7];
  const float* qw = (const float*)d_in[8];
  const float* kw = (const float*)d_in[9];

  uint16_t* p = (uint16_t*)d_ws;
  uint16_t* Xb   = p; p += (size_t)4096 * 1024;   // dead after gemmV
  uint16_t* Wqt  = p; p += (size_t)2048 * 1024;   // dead after gemmQ
  uint16_t* Wkt  = p; p += (size_t)1024 * 1024;
  uint16_t* Wvt  = p; p += (size_t)1024 * 1024;
  uint16_t* Wot  = p; p += (size_t)1024 * 2048;
  uint16_t* Qbuf = p; p += (size_t)B_ * H_ * S_ * D_;
  uint16_t* Kbuf = p; p += (size_t)B_ * HKV_ * S_ * D_;
  uint16_t* Vbuf = p; p += (size_t)B_ * HKV_ * S_ * D_;
  uint16_t* attn = p; p += (size_t)4096 * 2048;
  uint16_t* Vtb  = Xb;  // aliases Xb+Wqt head (both dead by vtrans time)

  castk<<<4096, 256, 0, stream>>>(hidden, Xb);
  transcast<<<dim3(64, 32), 256, 0, stream>>>(Wq, Wqt, 1024, 2048);
  transcast<<<dim3(32, 32), 256, 0, stream>>>(Wk, Wkt, 1024, 1024);
  transcast<<<dim3(32, 32), 256, 0, stream>>>(Wv, Wvt, 1024, 1024);
  transcast<<<dim3(32, 64), 256, 0, stream>>>(Wo, Wot, 2048, 1024);
  gemm_bt<<<dim3(16, 32), 256, 0, stream>>>(Xb, Wqt, Qbuf, 4096, 2048, 1024, 1, H_);
  gemm_bt<<<dim3(8, 32), 256, 0, stream>>>(Xb, Wkt, Kbuf, 4096, 1024, 1024, 1, HKV_);
  gemm_bt<<<dim3(8, 32), 256, 0, stream>>>(Xb, Wvt, Vbuf, 4096, 1024, 1024, 1, HKV_);
  vtrans<<<dim3(32, 2, 16), 256, 0, stream>>>(Vbuf, Vtb);
  norm_rope<<<24576, 256, 0, stream>>>(Qbuf, Kbuf, qw, kw, cosr, sinr);
  attn_kernel<<<2048, 64, 0, stream>>>(Qbuf, Kbuf, Vtb, attn);
  gemm_bt<<<dim3(8, 32), 256, 0, stream>>>(attn, Wot, d_out, 4096, 1024, 2048, 2, 0);
}

// Round 3
// 299.617 us; speedup vs baseline: 1.1792x; 1.0667x over previous
//
#include <hip/hip_runtime.h>
#include <stdint.h>

#define B_ 2
#define S_ 2048
#define H_ 16
#define HKV_ 8
#define D_ 128
#define EPS_ 1e-6f
#define SCALE_ 0.08838834764831845f

typedef __attribute__((ext_vector_type(8))) __bf16 bf16x8;
typedef __attribute__((ext_vector_type(4))) float f32x4;
typedef __attribute__((ext_vector_type(16))) float f32x16;

static __device__ __forceinline__ uint16_t f2b(float f) {
  uint32_t u = __builtin_bit_cast(uint32_t, f);
  u += 0x7fffu + ((u >> 16) & 1u);
  return (uint16_t)(u >> 16);
}
static __device__ __forceinline__ float b2f(uint16_t b) {
  uint32_t u = ((uint32_t)b) << 16;
  return __builtin_bit_cast(float, u);
}

typedef const __attribute__((address_space(1))) uint32_t* gas_p;
typedef __attribute__((address_space(3))) uint32_t* las_p;
static __device__ __forceinline__ void gload16(const void* g, void* l) {
  __builtin_amdgcn_global_load_lds((gas_p)g, (las_p)l, 16, 0, 0);
}

// ---------------- cast fp32 -> bf16 (4 elems/thread) ----------------
__global__ void castk(const float* __restrict__ in, uint16_t* __restrict__ out) {
  int i = blockIdx.x * 256 + threadIdx.x;
  float4 f = ((const float4*)in)[i];
  uint2 o;
  o.x = (uint32_t)f2b(f.x) | ((uint32_t)f2b(f.y) << 16);
  o.y = (uint32_t)f2b(f.z) | ((uint32_t)f2b(f.w) << 16);
  ((uint2*)out)[i] = o;
}

// ------------- transpose+cast: W (K x N fp32) -> Wt (N x K bf16) -------------
__global__ void transcast(const float* __restrict__ Wm, uint16_t* __restrict__ Wt,
                          int K, int N) {
  __shared__ float t[32][33];
  int nb = blockIdx.x * 32, kb = blockIdx.y * 32;
  int tx = threadIdx.x & 31, ty = threadIdx.x >> 5;
  #pragma unroll
  for (int i = ty; i < 32; i += 8) t[i][tx] = Wm[(size_t)(kb + i) * N + nb + tx];
  __syncthreads();
  #pragma unroll
  for (int i = ty; i < 32; i += 8) Wt[(size_t)(nb + i) * K + kb + tx] = f2b(t[tx][i]);
}

// ------------- bf16 transpose: V (bkv, s, 128) -> Vt (bkv, 128, s) -------------
__global__ __launch_bounds__(256) void vtrans(const uint16_t* __restrict__ Vin,
                                              uint16_t* __restrict__ Vt) {
  __shared__ uint16_t L[64 * 64];
  int s0 = blockIdx.x * 64, d0 = blockIdx.y * 64;
  const uint16_t* src = Vin + (size_t)blockIdx.z * S_ * D_;
  uint16_t* dst = Vt + (size_t)blockIdx.z * S_ * D_;
  int t = threadIdx.x;
  int rr = t >> 3, cb = t & 7;
  #pragma unroll
  for (int half = 0; half < 2; ++half) {
    int row = rr + half * 32;
    uint4 v = *(const uint4*)(src + (size_t)(s0 + row) * D_ + d0 + cb * 8);
    *(uint4*)(L + row * 64 + ((cb ^ (row & 7)) * 8)) = v;
  }
  __syncthreads();
  int dr = t >> 2, sc = (t & 3) * 16;
  union { uint16_t s[16]; uint4 q[2]; } u;
  #pragma unroll
  for (int j = 0; j < 16; ++j) {
    int s = sc + j;
    u.s[j] = L[s * 64 + (((dr >> 3) ^ (s & 7)) * 8) + (dr & 7)];
  }
  uint4* op = (uint4*)(dst + (size_t)(d0 + dr) * S_ + s0 + sc);
  op[0] = u.q[0];
  op[1] = u.q[1];
}

// ------------- GEMM: C = A(MxK,bf16,rm) * Bt(NxK,bf16,rm)^T -------------
__global__ __launch_bounds__(256) void gemm_bt(const uint16_t* __restrict__ A,
                                               const uint16_t* __restrict__ Bt,
                                               void* __restrict__ Cout,
                                               int M, int N, int K, int mode, int NH) {
  __shared__ uint16_t Al[128 * 64];
  __shared__ uint16_t Bl[128 * 64];
  int tid = threadIdx.x;
  int lane = tid & 63, lr = lane & 15, g = lane >> 4;
  int w = tid >> 6, wm = w >> 1, wn = w & 1;
  int wbase = w * 64;
  int m0 = blockIdx.y * 128, n0 = blockIdx.x * 128;
  f32x4 acc[4][4] = {};
  for (int k0 = 0; k0 < K; k0 += 64) {
    __syncthreads();
    #pragma unroll
    for (int p = 0; p < 4; ++p) {
      int c = tid + p * 256;
      int row = c >> 3, cb = c & 7;
      int sc = (cb ^ (row & 7)) * 8;
      gload16(A + (size_t)(m0 + row) * K + k0 + sc, Al + (size_t)(p * 256 + wbase) * 8);
      gload16(Bt + (size_t)(n0 + row) * K + k0 + sc, Bl + (size_t)(p * 256 + wbase) * 8);
    }
    __syncthreads();
    #pragma unroll
    for (int ks = 0; ks < 2; ++ks) {
      bf16x8 af[4], bfr[4];
      #pragma unroll
      for (int mi = 0; mi < 4; ++mi) {
        int row = wm * 64 + mi * 16 + lr;
        af[mi] = *(bf16x8*)((char*)Al + row * 128 + ((ks * 64 + g * 16) ^ ((row & 7) << 4)));
      }
      #pragma unroll
      for (int ni = 0; ni < 4; ++ni) {
        int row = wn * 64 + ni * 16 + lr;
        bfr[ni] = *(bf16x8*)((char*)Bl + row * 128 + ((ks * 64 + g * 16) ^ ((row & 7) << 4)));
      }
      __builtin_amdgcn_s_setprio(1);
      #pragma unroll
      for (int mi = 0; mi < 4; ++mi)
        #pragma unroll
        for (int ni = 0; ni < 4; ++ni)
          acc[mi][ni] = __builtin_amdgcn_mfma_f32_16x16x32_bf16(af[mi], bfr[ni], acc[mi][ni], 0, 0, 0);
      __builtin_amdgcn_s_setprio(0);
    }
  }
  #pragma unroll
  for (int mi = 0; mi < 4; ++mi)
    #pragma unroll
    for (int ni = 0; ni < 4; ++ni)
      #pragma unroll
      for (int e = 0; e < 4; ++e) {
        int row = m0 + wm * 64 + mi * 16 + 4 * g + e;
        int col = n0 + wn * 64 + ni * 16 + lr;
        float v = acc[mi][ni][e];
        if (mode == 2) {
          ((float*)Cout)[(size_t)row * N + col] = v;
        } else {
          int bb = row >> 11, s = row & 2047;
          int head = col >> 7, d = col & 127;
          ((uint16_t*)Cout)[(((size_t)(bb * NH + head)) * S_ + s) * D_ + d] = f2b(v);
        }
      }
}

// ------------- RMSNorm + RoPE (Q pre-scaled by 1/sqrt(D)) -------------
__global__ void norm_rope(uint16_t* __restrict__ Qb, uint16_t* __restrict__ Kb,
                          const float* __restrict__ qw, const float* __restrict__ kw,
                          const float* __restrict__ cosr, const float* __restrict__ sinr) {
  int row = blockIdx.x * 4 + (threadIdx.x >> 6);
  int lane = threadIdx.x & 63;
  int hh = row % 24;
  int bs = row / 24;
  int b = bs >> 11, s = bs & 2047;
  uint16_t* ptr;
  const float* wv;
  float sc;
  if (hh < H_) { ptr = Qb + (((size_t)(b * H_ + hh)) * S_ + s) * D_; wv = qw; sc = SCALE_; }
  else         { ptr = Kb + (((size_t)(b * HKV_ + (hh - H_))) * S_ + s) * D_; wv = kw; sc = 1.0f; }
  float x1 = b2f(ptr[lane]), x2 = b2f(ptr[lane + 64]);
  float ss = x1 * x1 + x2 * x2;
  #pragma unroll
  for (int msk = 1; msk < 64; msk <<= 1) ss += __shfl_xor(ss, msk, 64);
  float r = rsqrtf(ss * (1.0f / 128.0f) + EPS_);
  float n1 = x1 * r * wv[lane], n2 = x2 * r * wv[lane + 64];
  float c1 = cosr[s * 128 + lane], s1 = sinr[s * 128 + lane];
  float c2 = cosr[s * 128 + lane + 64], s2 = sinr[s * 128 + lane + 64];
  ptr[lane]      = f2b((n1 * c1 - n2 * s1) * sc);
  ptr[lane + 64] = f2b((n2 * c2 + n1 * s2) * sc);
}

// ------------- causal GQA flash attention, 32x32 MFMA, 1 wave / 32 q-rows -------------
#define LOADK(DST, KBN)                                                          \
  _Pragma("unroll") for (int t = 0; t < 8; ++t)                                  \
    DST[t] = *(const bf16x8*)(Kg + (size_t)((KBN) * 32 + ql) * D_ + t * 16 + 8 * hi);

#define ATTN_STEP(KC, KN) {                                                      \
  bf16x8 vf[4][2];                                                               \
  _Pragma("unroll") for (int dt = 0; dt < 4; ++dt)                               \
    _Pragma("unroll") for (int bk2 = 0; bk2 < 2; ++bk2)                          \
      vf[dt][bk2] = *(const bf16x8*)(Vg + (size_t)(dt * 32 + ql) * S_ + kb * 32 + bk2 * 16 + 8 * hi); \
  if (kb < qt) { LOADK(KN, kb + 1) }                                             \
  f32x16 acc = {};                                                               \
  __builtin_amdgcn_s_setprio(1);                                                 \
  _Pragma("unroll") for (int t = 0; t < 8; ++t)                                  \
    acc = __builtin_amdgcn_mfma_f32_32x32x16_bf16(KC[t], qf[t], acc, 0, 0, 0);   \
  __builtin_amdgcn_s_setprio(0);                                                 \
  float p[16];                                                                   \
  _Pragma("unroll") for (int r = 0; r < 16; ++r) p[r] = acc[r];                  \
  if (kb == qt) {                                                                \
    _Pragma("unroll") for (int r = 0; r < 16; ++r)                               \
      if (8 * (r >> 2) + 4 * hi + (r & 3) > ql) p[r] = -__builtin_inff();        \
  }                                                                              \
  float t8[8];                                                                   \
  _Pragma("unroll") for (int i = 0; i < 8; ++i) t8[i] = fmaxf(p[i], p[i + 8]);   \
  float t4a = fmaxf(t8[0], t8[4]), t4b = fmaxf(t8[1], t8[5]);                    \
  float t4c = fmaxf(t8[2], t8[6]), t4d = fmaxf(t8[3], t8[7]);                    \
  float pmax = fmaxf(fmaxf(t4a, t4b), fmaxf(t4c, t4d));                          \
  pmax = fmaxf(pmax, __shfl_xor(pmax, 32, 64));                                  \
  if (__any(pmax > mrun + 8.f)) {                                                \
    float mnew = fmaxf(mrun, pmax);                                              \
    float rs = __expf(mrun - mnew);                                              \
    lrun *= rs;                                                                  \
    _Pragma("unroll") for (int r = 0; r < 16; ++r) {                             \
      float rr = __shfl(rs, (r & 3) + 8 * (r >> 2) + 4 * hi, 64);                \
      _Pragma("unroll") for (int dt = 0; dt < 4; ++dt) O[dt][r] *= rr;           \
    }                                                                            \
    mrun = mnew;                                                                 \
  }                                                                              \
  float ls = 0.f;                                                                \
  _Pragma("unroll") for (int r = 0; r < 16; ++r) { p[r] = __expf(p[r] - mrun); ls += p[r]; } \
  ls += __shfl_xor(ls, 32, 64);                                                  \
  lrun += ls;                                                                    \
  uint32_t uu[4][2];                                                             \
  _Pragma("unroll") for (int T = 0; T < 4; ++T) {                                \
    asm("v_cvt_pk_bf16_f32 %0, %1, %2" : "=v"(uu[T][0]) : "v"(p[4 * T]), "v"(p[4 * T + 1]));     \
    asm("v_cvt_pk_bf16_f32 %0, %1, %2" : "=v"(uu[T][1]) : "v"(p[4 * T + 2]), "v"(p[4 * T + 3])); \
  }                                                                              \
  union PW { uint32_t w[4]; bf16x8 v; } pa0, pa1;                                \
  {                                                                              \
    uint32_t x0 = uu[0][0], y0 = uu[1][0];                                       \
    asm("v_permlane32_swap_b32 %0, %1" : "+v"(x0), "+v"(y0));                    \
    uint32_t x1 = uu[0][1], y1 = uu[1][1];                                       \
    asm("v_permlane32_swap_b32 %0, %1" : "+v"(x1), "+v"(y1));                    \
    pa0.w[0] = x0; pa0.w[1] = x1; pa0.w[2] = y0; pa0.w[3] = y1;                  \
    uint32_t x2 = uu[2][0], y2 = uu[3][0];                                       \
    asm("v_permlane32_swap_b32 %0, %1" : "+v"(x2), "+v"(y2));                    \
    uint32_t x3 = uu[2][1], y3 = uu[3][1];                                       \
    asm("v_permlane32_swap_b32 %0, %1" : "+v"(x3), "+v"(y3));                    \
    pa1.w[0] = x2; pa1.w[1] = x3; pa1.w[2] = y2; pa1.w[3] = y3;                  \
  }                                                                              \
  __builtin_amdgcn_s_setprio(1);                                                 \
  _Pragma("unroll") for (int dt = 0; dt < 4; ++dt) {                             \
    O[dt] = __builtin_amdgcn_mfma_f32_32x32x16_bf16(pa0.v, vf[dt][0], O[dt], 0, 0, 0); \
    O[dt] = __builtin_amdgcn_mfma_f32_32x32x16_bf16(pa1.v, vf[dt][1], O[dt], 0, 0, 0); \
  }                                                                              \
  __builtin_amdgcn_s_setprio(0);                                                 \
}

__global__ __launch_bounds__(64, 2) void attn_kernel(const uint16_t* __restrict__ Qb,
                                                     const uint16_t* __restrict__ Kb,
                                                     const uint16_t* __restrict__ Vtg,
                                                     uint16_t* __restrict__ out) {
  int lane = threadIdx.x & 63, ql = lane & 31, hi = lane >> 5;
  int wid = blockIdx.x;
  int x = wid & 7, rest = wid >> 3;
  int gsel = rest & 1, hsel = (rest >> 1) & 1, qidx = rest >> 2;
  int gkv = gsel * 8 + x;
  int b = gkv >> 3, kv = gkv & 7, h = kv * 2 + hsel;
  int qt = 63 - qidx;
  const uint16_t* Qg = Qb + ((size_t)(b * H_ + h)) * S_ * D_;
  const uint16_t* Kg = Kb + ((size_t)(b * HKV_ + kv)) * S_ * D_;
  const uint16_t* Vg = Vtg + ((size_t)(b * HKV_ + kv)) * S_ * D_;  // [128][2048]
  int q0 = qt * 32;
  bf16x8 qf[8];
  #pragma unroll
  for (int t = 0; t < 8; ++t)
    qf[t] = *(const bf16x8*)(Qg + (size_t)(q0 + ql) * D_ + t * 16 + 8 * hi);
  f32x16 O[4] = {};
  float mrun = -__builtin_inff();
  float lrun = 0.f;
  bf16x8 kfa[8], kfb[8];
  LOADK(kfa, 0)
  int kb = 0;
  for (;;) {
    ATTN_STEP(kfa, kfb)
    if (++kb > qt) break;
    ATTN_STEP(kfb, kfa)
    if (++kb > qt) break;
  }
  float linv = 1.0f / lrun;
  #pragma unroll
  for (int r = 0; r < 16; ++r) {
    int qrl = (r & 3) + 8 * (r >> 2) + 4 * hi;
    float lr_ = __shfl(linv, qrl, 64);
    #pragma unroll
    for (int dt = 0; dt < 4; ++dt) {
      size_t o = ((size_t)(b * S_ + q0 + qrl)) * 2048 + h * 128 + dt * 32 + ql;
      out[o] = f2b(O[dt][r] * lr_);
    }
  }
}

extern "C" void kernel_launch(void* const* d_in, const int* in_sizes, int n_in,
                              void* d_out, int out_size, void* d_ws, size_t ws_size,
                              hipStream_t stream) {
  const float* hidden = (const float*)d_in[0];
  const float* cosr = (const float*)d_in[2];
  const float* sinr = (const float*)d_in[3];
  const float* Wq = (const float*)d_in[4];
  const float* Wk = (const float*)d_in[5];
  const float* Wv = (const float*)d_in[6];
  const float* Wo = (const float*)d_in[7];
  const float* qw = (const float*)d_in[8];
  const float* kw = (const float*)d_in[9];

  uint16_t* p = (uint16_t*)d_ws;
  uint16_t* Xb   = p; p += (size_t)4096 * 1024;
  uint16_t* Wqt  = p; p += (size_t)2048 * 1024;
  uint16_t* Wkt  = p; p += (size_t)1024 * 1024;
  uint16_t* Wvt  = p; p += (size_t)1024 * 1024;
  uint16_t* Wot  = p; p += (size_t)1024 * 2048;
  uint16_t* Qbuf = p; p += (size_t)B_ * H_ * S_ * D_;
  uint16_t* Kbuf = p; p += (size_t)B_ * HKV_ * S_ * D_;
  uint16_t* Vbuf = p; p += (size_t)B_ * HKV_ * S_ * D_;
  uint16_t* attn = p; p += (size_t)4096 * 2048;
  uint16_t* Vtb  = Xb;  // aliases Xb (dead by vtrans time)

  castk<<<4096, 256, 0, stream>>>(hidden, Xb);
  transcast<<<dim3(64, 32), 256, 0, stream>>>(Wq, Wqt, 1024, 2048);
  transcast<<<dim3(32, 32), 256, 0, stream>>>(Wk, Wkt, 1024, 1024);
  transcast<<<dim3(32, 32), 256, 0, stream>>>(Wv, Wvt, 1024, 1024);
  transcast<<<dim3(32, 64), 256, 0, stream>>>(Wo, Wot, 2048, 1024);
  gemm_bt<<<dim3(16, 32), 256, 0, stream>>>(Xb, Wqt, Qbuf, 4096, 2048, 1024, 1, H_);
  gemm_bt<<<dim3(8, 32), 256, 0, stream>>>(Xb, Wkt, Kbuf, 4096, 1024, 1024, 1, HKV_);
  gemm_bt<<<dim3(8, 32), 256, 0, stream>>>(Xb, Wvt, Vbuf, 4096, 1024, 1024, 1, HKV_);
  vtrans<<<dim3(32, 2, 16), 256, 0, stream>>>(Vbuf, Vtb);
  norm_rope<<<24576, 256, 0, stream>>>(Qbuf, Kbuf, qw, kw, cosr, sinr);
  attn_kernel<<<2048, 64, 0, stream>>>(Qbuf, Kbuf, Vtb, attn);
  gemm_bt<<<dim3(8, 32), 256, 0, stream>>>(attn, Wot, d_out, 4096, 1024, 2048, 2, 0);
}

// Round 4
// 239.366 us; speedup vs baseline: 1.4760x; 1.2517x over previous
//
#include <hip/hip_runtime.h>
#include <stdint.h>

#define B_ 2
#define S_ 2048
#define H_ 16
#define HKV_ 8
#define D_ 128
#define EPS_ 1e-6f
#define SCALE_ 0.08838834764831845f

typedef __attribute__((ext_vector_type(8))) __bf16 bf16x8;
typedef __attribute__((ext_vector_type(4))) float f32x4;
typedef __attribute__((ext_vector_type(16))) float f32x16;

static __device__ __forceinline__ uint16_t f2b(float f) {
  uint32_t u = __builtin_bit_cast(uint32_t, f);
  u += 0x7fffu + ((u >> 16) & 1u);
  return (uint16_t)(u >> 16);
}
static __device__ __forceinline__ float b2f(uint16_t b) {
  uint32_t u = ((uint32_t)b) << 16;
  return __builtin_bit_cast(float, u);
}

typedef const __attribute__((address_space(1))) uint32_t* gas_p;
typedef __attribute__((address_space(3))) uint32_t* las_p;
static __device__ __forceinline__ void gload16(const void* g, void* l) {
  __builtin_amdgcn_global_load_lds((gas_p)g, (las_p)l, 16, 0, 0);
}

// ---------------- cast fp32 -> bf16 (4 elems/thread) ----------------
__global__ void castk(const float* __restrict__ in, uint16_t* __restrict__ out) {
  int i = blockIdx.x * 256 + threadIdx.x;
  float4 f = ((const float4*)in)[i];
  uint2 o;
  o.x = (uint32_t)f2b(f.x) | ((uint32_t)f2b(f.y) << 16);
  o.y = (uint32_t)f2b(f.z) | ((uint32_t)f2b(f.w) << 16);
  ((uint2*)out)[i] = o;
}

// ------------- transpose+cast: W (K x N fp32) -> Wt (N x K bf16) -------------
__global__ void transcast(const float* __restrict__ Wm, uint16_t* __restrict__ Wt,
                          int K, int N) {
  __shared__ float t[32][33];
  int nb = blockIdx.x * 32, kb = blockIdx.y * 32;
  int tx = threadIdx.x & 31, ty = threadIdx.x >> 5;
  #pragma unroll
  for (int i = ty; i < 32; i += 8) t[i][tx] = Wm[(size_t)(kb + i) * N + nb + tx];
  __syncthreads();
  #pragma unroll
  for (int i = ty; i < 32; i += 8) Wt[(size_t)(nb + i) * K + kb + tx] = f2b(t[tx][i]);
}

// ------------- bf16 transpose: V (bkv, s, 128) -> Vt (bkv, 128, s) -------------
__global__ __launch_bounds__(256) void vtrans(const uint16_t* __restrict__ Vin,
                                              uint16_t* __restrict__ Vt) {
  __shared__ uint16_t L[64 * 64];
  int s0 = blockIdx.x * 64, d0 = blockIdx.y * 64;
  const uint16_t* src = Vin + (size_t)blockIdx.z * S_ * D_;
  uint16_t* dst = Vt + (size_t)blockIdx.z * S_ * D_;
  int t = threadIdx.x;
  int rr = t >> 3, cb = t & 7;
  #pragma unroll
  for (int half = 0; half < 2; ++half) {
    int row = rr + half * 32;
    uint4 v = *(const uint4*)(src + (size_t)(s0 + row) * D_ + d0 + cb * 8);
    *(uint4*)(L + row * 64 + ((cb ^ (row & 7)) * 8)) = v;
  }
  __syncthreads();
  int dr = t >> 2, sc = (t & 3) * 16;
  union { uint16_t s[16]; uint4 q[2]; } u;
  #pragma unroll
  for (int j = 0; j < 16; ++j) {
    int s = sc + j;
    u.s[j] = L[s * 64 + (((dr >> 3) ^ (s & 7)) * 8) + (dr & 7)];
  }
  uint4* op = (uint4*)(dst + (size_t)(d0 + dr) * S_ + s0 + sc);
  op[0] = u.q[0];
  op[1] = u.q[1];
}

// ------------- GEMM: C = A(MxK,bf16,rm) * Bt(NxK,bf16,rm)^T -------------
__global__ __launch_bounds__(256) void gemm_bt(const uint16_t* __restrict__ A,
                                               const uint16_t* __restrict__ Bt,
                                               void* __restrict__ Cout,
                                               int M, int N, int K, int mode, int NH) {
  __shared__ uint16_t Al[128 * 64];
  __shared__ uint16_t Bl[128 * 64];
  int tid = threadIdx.x;
  int lane = tid & 63, lr = lane & 15, g = lane >> 4;
  int w = tid >> 6, wm = w >> 1, wn = w & 1;
  int wbase = w * 64;
  int m0 = blockIdx.y * 128, n0 = blockIdx.x * 128;
  f32x4 acc[4][4] = {};
  for (int k0 = 0; k0 < K; k0 += 64) {
    __syncthreads();
    #pragma unroll
    for (int p = 0; p < 4; ++p) {
      int c = tid + p * 256;
      int row = c >> 3, cb = c & 7;
      int sc = (cb ^ (row & 7)) * 8;
      gload16(A + (size_t)(m0 + row) * K + k0 + sc, Al + (size_t)(p * 256 + wbase) * 8);
      gload16(Bt + (size_t)(n0 + row) * K + k0 + sc, Bl + (size_t)(p * 256 + wbase) * 8);
    }
    __syncthreads();
    #pragma unroll
    for (int ks = 0; ks < 2; ++ks) {
      bf16x8 af[4], bfr[4];
      #pragma unroll
      for (int mi = 0; mi < 4; ++mi) {
        int row = wm * 64 + mi * 16 + lr;
        af[mi] = *(bf16x8*)((char*)Al + row * 128 + ((ks * 64 + g * 16) ^ ((row & 7) << 4)));
      }
      #pragma unroll
      for (int ni = 0; ni < 4; ++ni) {
        int row = wn * 64 + ni * 16 + lr;
        bfr[ni] = *(bf16x8*)((char*)Bl + row * 128 + ((ks * 64 + g * 16) ^ ((row & 7) << 4)));
      }
      __builtin_amdgcn_s_setprio(1);
      #pragma unroll
      for (int mi = 0; mi < 4; ++mi)
        #pragma unroll
        for (int ni = 0; ni < 4; ++ni)
          acc[mi][ni] = __builtin_amdgcn_mfma_f32_16x16x32_bf16(af[mi], bfr[ni], acc[mi][ni], 0, 0, 0);
      __builtin_amdgcn_s_setprio(0);
    }
  }
  #pragma unroll
  for (int mi = 0; mi < 4; ++mi)
    #pragma unroll
    for (int ni = 0; ni < 4; ++ni)
      #pragma unroll
      for (int e = 0; e < 4; ++e) {
        int row = m0 + wm * 64 + mi * 16 + 4 * g + e;
        int col = n0 + wn * 64 + ni * 16 + lr;
        float v = acc[mi][ni][e];
        if (mode == 2) {
          ((float*)Cout)[(size_t)row * N + col] = v;
        } else {
          int bb = row >> 11, s = row & 2047;
          int head = col >> 7, d = col & 127;
          ((uint16_t*)Cout)[(((size_t)(bb * NH + head)) * S_ + s) * D_ + d] = f2b(v);
        }
      }
}

// ------------- RMSNorm + RoPE (Q pre-scaled by 1/sqrt(D)) -------------
__global__ void norm_rope(uint16_t* __restrict__ Qb, uint16_t* __restrict__ Kb,
                          const float* __restrict__ qw, const float* __restrict__ kw,
                          const float* __restrict__ cosr, const float* __restrict__ sinr) {
  int row = blockIdx.x * 4 + (threadIdx.x >> 6);
  int lane = threadIdx.x & 63;
  int hh = row % 24;
  int bs = row / 24;
  int b = bs >> 11, s = bs & 2047;
  uint16_t* ptr;
  const float* wv;
  float sc;
  if (hh < H_) { ptr = Qb + (((size_t)(b * H_ + hh)) * S_ + s) * D_; wv = qw; sc = SCALE_; }
  else         { ptr = Kb + (((size_t)(b * HKV_ + (hh - H_))) * S_ + s) * D_; wv = kw; sc = 1.0f; }
  float x1 = b2f(ptr[lane]), x2 = b2f(ptr[lane + 64]);
  float ss = x1 * x1 + x2 * x2;
  #pragma unroll
  for (int msk = 1; msk < 64; msk <<= 1) ss += __shfl_xor(ss, msk, 64);
  float r = rsqrtf(ss * (1.0f / 128.0f) + EPS_);
  float n1 = x1 * r * wv[lane], n2 = x2 * r * wv[lane + 64];
  float c1 = cosr[s * 128 + lane], s1 = sinr[s * 128 + lane];
  float c2 = cosr[s * 128 + lane + 64], s2 = sinr[s * 128 + lane + 64];
  ptr[lane]      = f2b((n1 * c1 - n2 * s1) * sc);
  ptr[lane + 64] = f2b((n2 * c2 + n1 * s2) * sc);
}

// ------------- causal GQA flash attention, 32x32 MFMA -------------
// Block = 4 waves x 4 consecutive q-tiles sharing one KV stream staged in LDS.
// grid 512 x 256thr. K tile [32s][128d] swizzled g^=(row&7); V^T tile [128d][32s]
// swizzled g^=((d>>1)&3). Double-buffered; loads issued early, written after barrier.
__global__ __launch_bounds__(256, 2) void attn_kernel(const uint16_t* __restrict__ Qb,
                                                      const uint16_t* __restrict__ Kb,
                                                      const uint16_t* __restrict__ Vtg,
                                                      uint16_t* __restrict__ out) {
  __shared__ uint16_t Kl[2][32 * 128];
  __shared__ uint16_t Vl[2][128 * 32];
  int tid = threadIdx.x, lane = tid & 63, w = tid >> 6;
  int ql = lane & 31, hi = lane >> 5;
  int bi = blockIdx.x;
  int qg = 15 - (bi >> 5);            // longest q-groups first
  int rem = bi & 31;                  // (b,kv) pinned per XCD-ish; both h's adjacent
  int bkv = rem >> 1, hsel = rem & 1;
  int b = bkv >> 3, kv = bkv & 7, h = kv * 2 + hsel;
  int qt = qg * 4 + w, qtmax = qg * 4 + 3;
  const uint16_t* Qg = Qb + ((size_t)(b * H_ + h)) * S_ * D_;
  const uint16_t* Kg = Kb + ((size_t)(b * HKV_ + kv)) * S_ * D_;
  const uint16_t* Vg = Vtg + ((size_t)(b * HKV_ + kv)) * S_ * D_;  // [128][2048]
  int q0 = qt * 32;
  // staging coords (block-wide, 2 chunks of 16B each for K and V)
  int krow0 = tid >> 4, kg16 = tid & 15;          // K chunk 0: rows 0..15
  int vd0 = tid >> 2, vslot = tid & 3;            // V chunk 0: d 0..63
  char* kdst0 = (char*)nullptr;
  // Q fragments
  bf16x8 qf[8];
  #pragma unroll
  for (int t = 0; t < 8; ++t)
    qf[t] = *(const bf16x8*)(Qg + (size_t)(q0 + ql) * D_ + t * 16 + 8 * hi);
  f32x16 O[4] = {};
  float mrun = -__builtin_inff();
  float lrun = 0.f;
  // initial stage of kb=0 into buffer 0
  {
    uint4 k0 = *(const uint4*)(Kg + (size_t)krow0 * D_ + kg16 * 8);
    uint4 k1 = *(const uint4*)(Kg + (size_t)(krow0 + 16) * D_ + kg16 * 8);
    uint4 v0 = *(const uint4*)(Vg + (size_t)vd0 * S_ + vslot * 8);
    uint4 v1 = *(const uint4*)(Vg + (size_t)(vd0 + 64) * S_ + vslot * 8);
    *(uint4*)((char*)Kl[0] + krow0 * 256 + ((kg16 ^ (krow0 & 7)) * 16)) = k0;
    *(uint4*)((char*)Kl[0] + (krow0 + 16) * 256 + ((kg16 ^ ((krow0 + 16) & 7)) * 16)) = k1;
    *(uint4*)((char*)Vl[0] + vd0 * 64 + ((vslot ^ ((vd0 >> 1) & 3)) * 16)) = v0;
    *(uint4*)((char*)Vl[0] + (vd0 + 64) * 64 + ((vslot ^ (((vd0 + 64) >> 1) & 3)) * 16)) = v1;
  }
  for (int kb = 0; kb <= qtmax; ++kb) {
    int cur = kb & 1;
    __syncthreads();   // buf[cur] ready
    uint4 k0, k1, v0, v1;
    bool pf = (kb < qtmax);
    if (pf) {          // issue next-tile global loads early (latency hides under compute)
      int kbn = kb + 1;
      k0 = *(const uint4*)(Kg + (size_t)(kbn * 32 + krow0) * D_ + kg16 * 8);
      k1 = *(const uint4*)(Kg + (size_t)(kbn * 32 + krow0 + 16) * D_ + kg16 * 8);
      v0 = *(const uint4*)(Vg + (size_t)vd0 * S_ + kbn * 32 + vslot * 8);
      v1 = *(const uint4*)(Vg + (size_t)(vd0 + 64) * S_ + kbn * 32 + vslot * 8);
    }
    if (kb <= qt) {
      const char* KlC = (const char*)Kl[cur];
      const char* VlC = (const char*)Vl[cur];
      bf16x8 kf[8];
      #pragma unroll
      for (int t = 0; t < 8; ++t)
        kf[t] = *(const bf16x8*)(KlC + ql * 256 + (((2 * t + hi) ^ (ql & 7)) * 16));
      f32x16 acc = {};
      __builtin_amdgcn_s_setprio(1);
      #pragma unroll
      for (int t = 0; t < 8; ++t)
        acc = __builtin_amdgcn_mfma_f32_32x32x16_bf16(kf[t], qf[t], acc, 0, 0, 0);
      __builtin_amdgcn_s_setprio(0);
      float p[16];
      #pragma unroll
      for (int r = 0; r < 16; ++r) p[r] = acc[r];
      if (kb == qt) {
        #pragma unroll
        for (int r = 0; r < 16; ++r)
          if (8 * (r >> 2) + 4 * hi + (r & 3) > ql) p[r] = -__builtin_inff();
      }
      float t8[8];
      #pragma unroll
      for (int i = 0; i < 8; ++i) t8[i] = fmaxf(p[i], p[i + 8]);
      float t4a = fmaxf(t8[0], t8[4]), t4b = fmaxf(t8[1], t8[5]);
      float t4c = fmaxf(t8[2], t8[6]), t4d = fmaxf(t8[3], t8[7]);
      float pmax = fmaxf(fmaxf(t4a, t4b), fmaxf(t4c, t4d));
      pmax = fmaxf(pmax, __shfl_xor(pmax, 32, 64));
      if (__any(pmax > mrun + 8.f)) {
        float mnew = fmaxf(mrun, pmax);
        float rs = __expf(mrun - mnew);
        lrun *= rs;
        #pragma unroll
        for (int r = 0; r < 16; ++r) {
          float rr = __shfl(rs, (r & 3) + 8 * (r >> 2) + 4 * hi, 64);
          #pragma unroll
          for (int dt = 0; dt < 4; ++dt) O[dt][r] *= rr;
        }
        mrun = mnew;
      }
      float ls = 0.f;
      #pragma unroll
      for (int r = 0; r < 16; ++r) { p[r] = __expf(p[r] - mrun); ls += p[r]; }
      ls += __shfl_xor(ls, 32, 64);
      lrun += ls;
      uint32_t uu[4][2];
      #pragma unroll
      for (int T = 0; T < 4; ++T) {
        asm("v_cvt_pk_bf16_f32 %0, %1, %2" : "=v"(uu[T][0]) : "v"(p[4 * T]), "v"(p[4 * T + 1]));
        asm("v_cvt_pk_bf16_f32 %0, %1, %2" : "=v"(uu[T][1]) : "v"(p[4 * T + 2]), "v"(p[4 * T + 3]));
      }
      union PW { uint32_t w[4]; bf16x8 v; } pa0, pa1;
      {
        uint32_t x0 = uu[0][0], y0 = uu[1][0];
        asm("v_permlane32_swap_b32 %0, %1" : "+v"(x0), "+v"(y0));
        uint32_t x1 = uu[0][1], y1 = uu[1][1];
        asm("v_permlane32_swap_b32 %0, %1" : "+v"(x1), "+v"(y1));
        pa0.w[0] = x0; pa0.w[1] = x1; pa0.w[2] = y0; pa0.w[3] = y1;
        uint32_t x2 = uu[2][0], y2 = uu[3][0];
        asm("v_permlane32_swap_b32 %0, %1" : "+v"(x2), "+v"(y2));
        uint32_t x3 = uu[2][1], y3 = uu[3][1];
        asm("v_permlane32_swap_b32 %0, %1" : "+v"(x3), "+v"(y3));
        pa1.w[0] = x2; pa1.w[1] = x3; pa1.w[2] = y2; pa1.w[3] = y3;
      }
      bf16x8 vf[8];
      #pragma unroll
      for (int dt = 0; dt < 4; ++dt)
        #pragma unroll
        for (int bk2 = 0; bk2 < 2; ++bk2)
          vf[dt * 2 + bk2] = *(const bf16x8*)(VlC + (dt * 32 + ql) * 64 +
                                              (((bk2 * 2 + hi) ^ ((ql >> 1) & 3)) * 16));
      __builtin_amdgcn_s_setprio(1);
      #pragma unroll
      for (int dt = 0; dt < 4; ++dt) {
        O[dt] = __builtin_amdgcn_mfma_f32_32x32x16_bf16(pa0.v, vf[dt * 2 + 0], O[dt], 0, 0, 0);
        O[dt] = __builtin_amdgcn_mfma_f32_32x32x16_bf16(pa1.v, vf[dt * 2 + 1], O[dt], 0, 0, 0);
      }
      __builtin_amdgcn_s_setprio(0);
    }
    __syncthreads();   // all reads of buf[cur^1] (prev iter) done
    if (pf) {
      int nb = cur ^ 1;
      *(uint4*)((char*)Kl[nb] + krow0 * 256 + ((kg16 ^ (krow0 & 7)) * 16)) = k0;
      *(uint4*)((char*)Kl[nb] + (krow0 + 16) * 256 + ((kg16 ^ ((krow0 + 16) & 7)) * 16)) = k1;
      *(uint4*)((char*)Vl[nb] + vd0 * 64 + ((vslot ^ ((vd0 >> 1) & 3)) * 16)) = v0;
      *(uint4*)((char*)Vl[nb] + (vd0 + 64) * 64 + ((vslot ^ (((vd0 + 64) >> 1) & 3)) * 16)) = v1;
    }
  }
  float linv = 1.0f / lrun;
  #pragma unroll
  for (int r = 0; r < 16; ++r) {
    int qrl = (r & 3) + 8 * (r >> 2) + 4 * hi;
    float lr_ = __shfl(linv, qrl, 64);
    #pragma unroll
    for (int dt = 0; dt < 4; ++dt) {
      size_t o = ((size_t)(b * S_ + q0 + qrl)) * 2048 + h * 128 + dt * 32 + ql;
      out[o] = f2b(O[dt][r] * lr_);
    }
  }
}

extern "C" void kernel_launch(void* const* d_in, const int* in_sizes, int n_in,
                              void* d_out, int out_size, void* d_ws, size_t ws_size,
                              hipStream_t stream) {
  const float* hidden = (const float*)d_in[0];
  const float* cosr = (const float*)d_in[2];
  const float* sinr = (const float*)d_in[3];
  const float* Wq = (const float*)d_in[4];
  const float* Wk = (const float*)d_in[5];
  const float* Wv = (const float*)d_in[6];
  const float* Wo = (const float*)d_in[7];
  const float* qw = (const float*)d_in[8];
  const float* kw = (const float*)d_in[9];

  uint16_t* p = (uint16_t*)d_ws;
  uint16_t* Xb   = p; p += (size_t)4096 * 1024;
  uint16_t* Wqt  = p; p += (size_t)2048 * 1024;
  uint16_t* Wkt  = p; p += (size_t)1024 * 1024;
  uint16_t* Wvt  = p; p += (size_t)1024 * 1024;
  uint16_t* Wot  = p; p += (size_t)1024 * 2048;
  uint16_t* Qbuf = p; p += (size_t)B_ * H_ * S_ * D_;
  uint16_t* Kbuf = p; p += (size_t)B_ * HKV_ * S_ * D_;
  uint16_t* Vbuf = p; p += (size_t)B_ * HKV_ * S_ * D_;
  uint16_t* attn = p; p += (size_t)4096 * 2048;
  uint16_t* Vtb  = Xb;  // aliases Xb (dead by vtrans time)

  castk<<<4096, 256, 0, stream>>>(hidden, Xb);
  transcast<<<dim3(64, 32), 256, 0, stream>>>(Wq, Wqt, 1024, 2048);
  transcast<<<dim3(32, 32), 256, 0, stream>>>(Wk, Wkt, 1024, 1024);
  transcast<<<dim3(32, 32), 256, 0, stream>>>(Wv, Wvt, 1024, 1024);
  transcast<<<dim3(32, 64), 256, 0, stream>>>(Wo, Wot, 2048, 1024);
  gemm_bt<<<dim3(16, 32), 256, 0, stream>>>(Xb, Wqt, Qbuf, 4096, 2048, 1024, 1, H_);
  gemm_bt<<<dim3(8, 32), 256, 0, stream>>>(Xb, Wkt, Kbuf, 4096, 1024, 1024, 1, HKV_);
  gemm_bt<<<dim3(8, 32), 256, 0, stream>>>(Xb, Wvt, Vbuf, 4096, 1024, 1024, 1, HKV_);
  vtrans<<<dim3(32, 2, 16), 256, 0, stream>>>(Vbuf, Vtb);
  norm_rope<<<24576, 256, 0, stream>>>(Qbuf, Kbuf, qw, kw, cosr, sinr);
  attn_kernel<<<512, 256, 0, stream>>>(Qbuf, Kbuf, Vtb, attn);
  gemm_bt<<<dim3(8, 32), 256, 0, stream>>>(attn, Wot, d_out, 4096, 1024, 2048, 2, 0);
}

// Round 5
// 229.649 us; speedup vs baseline: 1.5385x; 1.0423x over previous
//
#include <hip/hip_runtime.h>
#include <stdint.h>

#define B_ 2
#define S_ 2048
#define H_ 16
#define HKV_ 8
#define D_ 128
#define EPS_ 1e-6f
#define SCALE_ 0.08838834764831845f

typedef __attribute__((ext_vector_type(8))) __bf16 bf16x8;
typedef __attribute__((ext_vector_type(4))) float f32x4;
typedef __attribute__((ext_vector_type(16))) float f32x16;

static __device__ __forceinline__ uint16_t f2b(float f) {
  uint32_t u = __builtin_bit_cast(uint32_t, f);
  u += 0x7fffu + ((u >> 16) & 1u);
  return (uint16_t)(u >> 16);
}
static __device__ __forceinline__ float b2f(uint16_t b) {
  uint32_t u = ((uint32_t)b) << 16;
  return __builtin_bit_cast(float, u);
}

typedef const __attribute__((address_space(1))) uint32_t* gas_p;
typedef __attribute__((address_space(3))) uint32_t* las_p;
static __device__ __forceinline__ void gload16(const void* g, void* l) {
  __builtin_amdgcn_global_load_lds((gas_p)g, (las_p)l, 16, 0, 0);
}

// ---------------- cast fp32 -> bf16 (4 elems/thread) ----------------
__global__ void castk(const float* __restrict__ in, uint16_t* __restrict__ out) {
  int i = blockIdx.x * 256 + threadIdx.x;
  float4 f = ((const float4*)in)[i];
  uint2 o;
  o.x = (uint32_t)f2b(f.x) | ((uint32_t)f2b(f.y) << 16);
  o.y = (uint32_t)f2b(f.z) | ((uint32_t)f2b(f.w) << 16);
  ((uint2*)out)[i] = o;
}

// ------------- transpose+cast: W (K x N fp32) -> Wt (N x K bf16) -------------
__global__ void transcast(const float* __restrict__ Wm, uint16_t* __restrict__ Wt,
                          int K, int N) {
  __shared__ float t[32][33];
  int nb = blockIdx.x * 32, kb = blockIdx.y * 32;
  int tx = threadIdx.x & 31, ty = threadIdx.x >> 5;
  #pragma unroll
  for (int i = ty; i < 32; i += 8) t[i][tx] = Wm[(size_t)(kb + i) * N + nb + tx];
  __syncthreads();
  #pragma unroll
  for (int i = ty; i < 32; i += 8) Wt[(size_t)(nb + i) * K + kb + tx] = f2b(t[tx][i]);
}

// ------------- bf16 transpose: V (bkv, s, 128) -> Vt (bkv, 128, s) -------------
__global__ __launch_bounds__(256) void vtrans(const uint16_t* __restrict__ Vin,
                                              uint16_t* __restrict__ Vt) {
  __shared__ uint16_t L[64 * 64];
  int s0 = blockIdx.x * 64, d0 = blockIdx.y * 64;
  const uint16_t* src = Vin + (size_t)blockIdx.z * S_ * D_;
  uint16_t* dst = Vt + (size_t)blockIdx.z * S_ * D_;
  int t = threadIdx.x;
  int rr = t >> 3, cb = t & 7;
  #pragma unroll
  for (int half = 0; half < 2; ++half) {
    int row = rr + half * 32;
    uint4 v = *(const uint4*)(src + (size_t)(s0 + row) * D_ + d0 + cb * 8);
    *(uint4*)(L + row * 64 + ((cb ^ (row & 7)) * 8)) = v;
  }
  __syncthreads();
  int dr = t >> 2, sc = (t & 3) * 16;
  union { uint16_t s[16]; uint4 q[2]; } u;
  #pragma unroll
  for (int j = 0; j < 16; ++j) {
    int s = sc + j;
    u.s[j] = L[s * 64 + (((dr >> 3) ^ (s & 7)) * 8) + (dr & 7)];
  }
  uint4* op = (uint4*)(dst + (size_t)(d0 + dr) * S_ + s0 + sc);
  op[0] = u.q[0];
  op[1] = u.q[1];
}

// ------------- GEMM: C = A(MxK,bf16,rm) * Bt(NxK,bf16,rm)^T -------------
__global__ __launch_bounds__(256) void gemm_bt(const uint16_t* __restrict__ A,
                                               const uint16_t* __restrict__ Bt,
                                               void* __restrict__ Cout,
                                               int M, int N, int K, int mode, int NH) {
  __shared__ uint16_t Al[128 * 64];
  __shared__ uint16_t Bl[128 * 64];
  int tid = threadIdx.x;
  int lane = tid & 63, lr = lane & 15, g = lane >> 4;
  int w = tid >> 6, wm = w >> 1, wn = w & 1;
  int wbase = w * 64;
  int m0 = blockIdx.y * 128, n0 = blockIdx.x * 128;
  f32x4 acc[4][4] = {};
  for (int k0 = 0; k0 < K; k0 += 64) {
    __syncthreads();
    #pragma unroll
    for (int p = 0; p < 4; ++p) {
      int c = tid + p * 256;
      int row = c >> 3, cb = c & 7;
      int sc = (cb ^ (row & 7)) * 8;
      gload16(A + (size_t)(m0 + row) * K + k0 + sc, Al + (size_t)(p * 256 + wbase) * 8);
      gload16(Bt + (size_t)(n0 + row) * K + k0 + sc, Bl + (size_t)(p * 256 + wbase) * 8);
    }
    __syncthreads();
    #pragma unroll
    for (int ks = 0; ks < 2; ++ks) {
      bf16x8 af[4], bfr[4];
      #pragma unroll
      for (int mi = 0; mi < 4; ++mi) {
        int row = wm * 64 + mi * 16 + lr;
        af[mi] = *(bf16x8*)((char*)Al + row * 128 + ((ks * 64 + g * 16) ^ ((row & 7) << 4)));
      }
      #pragma unroll
      for (int ni = 0; ni < 4; ++ni) {
        int row = wn * 64 + ni * 16 + lr;
        bfr[ni] = *(bf16x8*)((char*)Bl + row * 128 + ((ks * 64 + g * 16) ^ ((row & 7) << 4)));
      }
      __builtin_amdgcn_s_setprio(1);
      #pragma unroll
      for (int mi = 0; mi < 4; ++mi)
        #pragma unroll
        for (int ni = 0; ni < 4; ++ni)
          acc[mi][ni] = __builtin_amdgcn_mfma_f32_16x16x32_bf16(af[mi], bfr[ni], acc[mi][ni], 0, 0, 0);
      __builtin_amdgcn_s_setprio(0);
    }
  }
  #pragma unroll
  for (int mi = 0; mi < 4; ++mi)
    #pragma unroll
    for (int ni = 0; ni < 4; ++ni)
      #pragma unroll
      for (int e = 0; e < 4; ++e) {
        int row = m0 + wm * 64 + mi * 16 + 4 * g + e;
        int col = n0 + wn * 64 + ni * 16 + lr;
        float v = acc[mi][ni][e];
        if (mode == 2) {
          ((float*)Cout)[(size_t)row * N + col] = v;
        } else {
          int bb = row >> 11, s = row & 2047;
          int head = col >> 7, d = col & 127;
          ((uint16_t*)Cout)[(((size_t)(bb * NH + head)) * S_ + s) * D_ + d] = f2b(v);
        }
      }
}

// ------------- RMSNorm + RoPE (Q pre-scaled by 1/sqrt(D)) -------------
__global__ void norm_rope(uint16_t* __restrict__ Qb, uint16_t* __restrict__ Kb,
                          const float* __restrict__ qw, const float* __restrict__ kw,
                          const float* __restrict__ cosr, const float* __restrict__ sinr) {
  int row = blockIdx.x * 4 + (threadIdx.x >> 6);
  int lane = threadIdx.x & 63;
  int hh = row % 24;
  int bs = row / 24;
  int b = bs >> 11, s = bs & 2047;
  uint16_t* ptr;
  const float* wv;
  float sc;
  if (hh < H_) { ptr = Qb + (((size_t)(b * H_ + hh)) * S_ + s) * D_; wv = qw; sc = SCALE_; }
  else         { ptr = Kb + (((size_t)(b * HKV_ + (hh - H_))) * S_ + s) * D_; wv = kw; sc = 1.0f; }
  float x1 = b2f(ptr[lane]), x2 = b2f(ptr[lane + 64]);
  float ss = x1 * x1 + x2 * x2;
  #pragma unroll
  for (int msk = 1; msk < 64; msk <<= 1) ss += __shfl_xor(ss, msk, 64);
  float r = rsqrtf(ss * (1.0f / 128.0f) + EPS_);
  float n1 = x1 * r * wv[lane], n2 = x2 * r * wv[lane + 64];
  float c1 = cosr[s * 128 + lane], s1 = sinr[s * 128 + lane];
  float c2 = cosr[s * 128 + lane + 64], s2 = sinr[s * 128 + lane + 64];
  ptr[lane]      = f2b((n1 * c1 - n2 * s1) * sc);
  ptr[lane + 64] = f2b((n2 * c2 + n1 * s2) * sc);
}

// ------------- causal GQA flash attention, 32x32 MFMA, KVBLK=64 -------------
// Block = 4 waves x 4 consecutive q-tiles sharing one KV stream.
// global_load_lds staging (linear LDS dest, inverse-swizzled global src),
// double-buffered, ONE barrier per 64-key iteration (implicit vmcnt drain
// covers loads issued one full iteration earlier).
#define STAGE(BUF, KB) {                                                       \
  int kb64 = (KB) * 64;                                                        \
  _Pragma("unroll") for (int p2 = 0; p2 < 4; ++p2) {                           \
    int ck = p2 * 4 + w;                                                       \
    int krow = ck * 4 + (lane >> 4);                                           \
    int kg = (lane & 15) ^ (krow & 7);                                         \
    gload16(Kg + (size_t)(kb64 + krow) * D_ + kg * 8, Kl[BUF] + ck * 512);     \
    int vrow = ck * 8 + (lane >> 3);                                           \
    int vg = (lane & 7) ^ (vrow & 7);                                          \
    gload16(Vg + (size_t)vrow * S_ + kb64 + vg * 8, Vl[BUF] + ck * 512);       \
  } }

__global__ __launch_bounds__(256, 2) void attn_kernel(const uint16_t* __restrict__ Qb,
                                                      const uint16_t* __restrict__ Kb,
                                                      const uint16_t* __restrict__ Vtg,
                                                      uint16_t* __restrict__ out) {
  __shared__ uint16_t Kl[2][64 * 128];
  __shared__ uint16_t Vl[2][128 * 64];
  int tid = threadIdx.x, lane = tid & 63, w = tid >> 6;
  int ql = lane & 31, hi = lane >> 5;
  int bi = blockIdx.x;
  int qg = 15 - (bi >> 5);            // longest q-groups first
  int rem = bi & 31;
  int bkv = rem >> 1, hsel = rem & 1;
  int b = bkv >> 3, kv = bkv & 7, h = kv * 2 + hsel;
  int qt = qg * 4 + w;
  int q0 = qt * 32;
  int mykb = qt >> 1;                 // last KV block this wave computes
  int kbmax = 2 * qg + 1;             // last KV block any wave in block computes
  const uint16_t* Qg = Qb + ((size_t)(b * H_ + h)) * S_ * D_;
  const uint16_t* Kg = Kb + ((size_t)(b * HKV_ + kv)) * S_ * D_;
  const uint16_t* Vg = Vtg + ((size_t)(b * HKV_ + kv)) * S_ * D_;  // [128][2048]
  bf16x8 qf[8];
  #pragma unroll
  for (int t = 0; t < 8; ++t)
    qf[t] = *(const bf16x8*)(Qg + (size_t)(q0 + ql) * D_ + t * 16 + 8 * hi);
  f32x16 O[4] = {};
  float mrun = -__builtin_inff();
  float lrun = 0.f;
  STAGE(0, 0)
  for (int kb = 0; kb <= kbmax; ++kb) {
    int cur = kb & 1;
    __syncthreads();                  // implicit vmcnt(0): buf[cur] staged; all waves synced
    if (kb < kbmax) STAGE(cur ^ 1, kb + 1)
    if (kb <= mykb) {
      const uint16_t* KlC = Kl[cur];
      const uint16_t* VlC = Vl[cur];
      float p[32];
      #pragma unroll
      for (int half = 0; half < 2; ++half) {
        bf16x8 kf[8];
        #pragma unroll
        for (int t = 0; t < 8; ++t)
          kf[t] = *(const bf16x8*)(KlC + (half * 32 + ql) * 128 + (((2 * t + hi) ^ (ql & 7)) * 8));
        f32x16 acc = {};
        __builtin_amdgcn_s_setprio(1);
        #pragma unroll
        for (int t = 0; t < 8; ++t)
          acc = __builtin_amdgcn_mfma_f32_32x32x16_bf16(kf[t], qf[t], acc, 0, 0, 0);
        __builtin_amdgcn_s_setprio(0);
        #pragma unroll
        for (int r = 0; r < 16; ++r) p[half * 16 + r] = acc[r];
      }
      if (kb == mykb) {               // diagonal block: causal mask
        #pragma unroll
        for (int half = 0; half < 2; ++half)
          #pragma unroll
          for (int r = 0; r < 16; ++r) {
            int kk = kb * 64 + half * 32 + 8 * (r >> 2) + 4 * hi + (r & 3);
            if (kk > q0 + ql) p[half * 16 + r] = -__builtin_inff();
          }
      }
      float m16[16];
      #pragma unroll
      for (int i = 0; i < 16; ++i) m16[i] = fmaxf(p[i], p[i + 16]);
      float m8[8];
      #pragma unroll
      for (int i = 0; i < 8; ++i) m8[i] = fmaxf(m16[i], m16[i + 8]);
      float m4a = fmaxf(m8[0], m8[4]), m4b = fmaxf(m8[1], m8[5]);
      float m4c = fmaxf(m8[2], m8[6]), m4d = fmaxf(m8[3], m8[7]);
      float pmax = fmaxf(fmaxf(m4a, m4b), fmaxf(m4c, m4d));
      pmax = fmaxf(pmax, __shfl_xor(pmax, 32, 64));
      if (__any(pmax > mrun + 8.f)) {
        float mnew = fmaxf(mrun, pmax);
        float rs = __expf(mrun - mnew);
        lrun *= rs;
        #pragma unroll
        for (int r = 0; r < 16; ++r) {
          float rr = __shfl(rs, (r & 3) + 8 * (r >> 2) + 4 * hi, 64);
          #pragma unroll
          for (int dt = 0; dt < 4; ++dt) O[dt][r] *= rr;
        }
        mrun = mnew;
      }
      float ls = 0.f;
      #pragma unroll
      for (int r = 0; r < 32; ++r) { p[r] = __expf(p[r] - mrun); ls += p[r]; }
      ls += __shfl_xor(ls, 32, 64);
      lrun += ls;
      uint32_t uu[8][2];
      #pragma unroll
      for (int T = 0; T < 8; ++T) {
        asm("v_cvt_pk_bf16_f32 %0, %1, %2" : "=v"(uu[T][0]) : "v"(p[4 * T]), "v"(p[4 * T + 1]));
        asm("v_cvt_pk_bf16_f32 %0, %1, %2" : "=v"(uu[T][1]) : "v"(p[4 * T + 2]), "v"(p[4 * T + 3]));
      }
      union PW { uint32_t w[4]; bf16x8 v; } pa[4];
      #pragma unroll
      for (int P = 0; P < 4; ++P) {
        uint32_t a = uu[2 * P][0], bb2 = uu[2 * P + 1][0];
        asm("v_permlane32_swap_b32 %0, %1" : "+v"(a), "+v"(bb2));
        uint32_t c = uu[2 * P][1], d = uu[2 * P + 1][1];
        asm("v_permlane32_swap_b32 %0, %1" : "+v"(c), "+v"(d));
        pa[P].w[0] = a; pa[P].w[1] = c; pa[P].w[2] = bb2; pa[P].w[3] = d;
      }
      __builtin_amdgcn_s_setprio(1);
      #pragma unroll
      for (int dt = 0; dt < 4; ++dt) {
        #pragma unroll
        for (int j = 0; j < 4; ++j) {
          bf16x8 vfr = *(const bf16x8*)(VlC + (dt * 32 + ql) * 64 + (((2 * j + hi) ^ (ql & 7)) * 8));
          O[dt] = __builtin_amdgcn_mfma_f32_32x32x16_bf16(pa[j].v, vfr, O[dt], 0, 0, 0);
        }
      }
      __builtin_amdgcn_s_setprio(0);
    }
  }
  float linv = 1.0f / lrun;
  #pragma unroll
  for (int r = 0; r < 16; ++r) {
    int qrl = (r & 3) + 8 * (r >> 2) + 4 * hi;
    float lr_ = __shfl(linv, qrl, 64);
    #pragma unroll
    for (int dt = 0; dt < 4; ++dt) {
      size_t o = ((size_t)(b * S_ + q0 + qrl)) * 2048 + h * 128 + dt * 32 + ql;
      out[o] = f2b(O[dt][r] * lr_);
    }
  }
}

extern "C" void kernel_launch(void* const* d_in, const int* in_sizes, int n_in,
                              void* d_out, int out_size, void* d_ws, size_t ws_size,
                              hipStream_t stream) {
  const float* hidden = (const float*)d_in[0];
  const float* cosr = (const float*)d_in[2];
  const float* sinr = (const float*)d_in[3];
  const float* Wq = (const float*)d_in[4];
  const float* Wk = (const float*)d_in[5];
  const float* Wv = (const float*)d_in[6];
  const float* Wo = (const float*)d_in[7];
  const float* qw = (const float*)d_in[8];
  const float* kw = (const float*)d_in[9];

  uint16_t* p = (uint16_t*)d_ws;
  uint16_t* Xb   = p; p += (size_t)4096 * 1024;
  uint16_t* Wqt  = p; p += (size_t)2048 * 1024;
  uint16_t* Wkt  = p; p += (size_t)1024 * 1024;
  uint16_t* Wvt  = p; p += (size_t)1024 * 1024;
  uint16_t* Wot  = p; p += (size_t)1024 * 2048;
  uint16_t* Qbuf = p; p += (size_t)B_ * H_ * S_ * D_;
  uint16_t* Kbuf = p; p += (size_t)B_ * HKV_ * S_ * D_;
  uint16_t* Vbuf = p; p += (size_t)B_ * HKV_ * S_ * D_;
  uint16_t* attn = p; p += (size_t)4096 * 2048;
  uint16_t* Vtb  = Xb;  // aliases Xb (dead by vtrans time)

  castk<<<4096, 256, 0, stream>>>(hidden, Xb);
  transcast<<<dim3(64, 32), 256, 0, stream>>>(Wq, Wqt, 1024, 2048);
  transcast<<<dim3(32, 32), 256, 0, stream>>>(Wk, Wkt, 1024, 1024);
  transcast<<<dim3(32, 32), 256, 0, stream>>>(Wv, Wvt, 1024, 1024);
  transcast<<<dim3(32, 64), 256, 0, stream>>>(Wo, Wot, 2048, 1024);
  gemm_bt<<<dim3(16, 32), 256, 0, stream>>>(Xb, Wqt, Qbuf, 4096, 2048, 1024, 1, H_);
  gemm_bt<<<dim3(8, 32), 256, 0, stream>>>(Xb, Wkt, Kbuf, 4096, 1024, 1024, 1, HKV_);
  gemm_bt<<<dim3(8, 32), 256, 0, stream>>>(Xb, Wvt, Vbuf, 4096, 1024, 1024, 1, HKV_);
  vtrans<<<dim3(32, 2, 16), 256, 0, stream>>>(Vbuf, Vtb);
  norm_rope<<<24576, 256, 0, stream>>>(Qbuf, Kbuf, qw, kw, cosr, sinr);
  attn_kernel<<<512, 256, 0, stream>>>(Qbuf, Kbuf, Vtb, attn);
  gemm_bt<<<dim3(8, 32), 256, 0, stream>>>(attn, Wot, d_out, 4096, 1024, 2048, 2, 0);
}

// Round 6
// 204.646 us; speedup vs baseline: 1.7265x; 1.1222x over previous
//
#include <hip/hip_runtime.h>
#include <stdint.h>

#define B_ 2
#define S_ 2048
#define H_ 16
#define HKV_ 8
#define D_ 128
#define EPS_ 1e-6f
#define SCALE_ 0.08838834764831845f
#define QSZ_ 8388608     // B*H*S*D
#define KSZ_ 4194304     // B*HKV*S*D

typedef __attribute__((ext_vector_type(8))) __bf16 bf16x8;
typedef __attribute__((ext_vector_type(4))) float f32x4;
typedef __attribute__((ext_vector_type(16))) float f32x16;

static __device__ __forceinline__ uint16_t f2b(float f) {
  uint32_t u = __builtin_bit_cast(uint32_t, f);
  u += 0x7fffu + ((u >> 16) & 1u);
  return (uint16_t)(u >> 16);
}
static __device__ __forceinline__ float b2f(uint16_t b) {
  uint32_t u = ((uint32_t)b) << 16;
  return __builtin_bit_cast(float, u);
}

typedef const __attribute__((address_space(1))) uint32_t* gas_p;
typedef __attribute__((address_space(3))) uint32_t* las_p;
static __device__ __forceinline__ void gload16(const void* g, void* l) {
  __builtin_amdgcn_global_load_lds((gas_p)g, (las_p)l, 16, 0, 0);
}

// ---------------- cast fp32 -> bf16 (4 elems/thread) ----------------
__global__ void castk(const float* __restrict__ in, uint16_t* __restrict__ out) {
  int i = blockIdx.x * 256 + threadIdx.x;
  float4 f = ((const float4*)in)[i];
  uint2 o;
  o.x = (uint32_t)f2b(f.x) | ((uint32_t)f2b(f.y) << 16);
  o.y = (uint32_t)f2b(f.z) | ((uint32_t)f2b(f.w) << 16);
  ((uint2*)out)[i] = o;
}

// ------------- transpose+cast: W (K x N fp32) -> Wt (N x K bf16) -------------
__global__ void transcast(const float* __restrict__ Wm, uint16_t* __restrict__ Wt,
                          int K, int N) {
  __shared__ float t[32][33];
  int nb = blockIdx.x * 32, kb = blockIdx.y * 32;
  int tx = threadIdx.x & 31, ty = threadIdx.x >> 5;
  #pragma unroll
  for (int i = ty; i < 32; i += 8) t[i][tx] = Wm[(size_t)(kb + i) * N + nb + tx];
  __syncthreads();
  #pragma unroll
  for (int i = ty; i < 32; i += 8) Wt[(size_t)(nb + i) * K + kb + tx] = f2b(t[tx][i]);
}

// ------------- bf16 transpose: V (bkv, s, 128) -> Vt (bkv, 128, s) -------------
__global__ __launch_bounds__(256) void vtrans(const uint16_t* __restrict__ Vin,
                                              uint16_t* __restrict__ Vt) {
  __shared__ uint16_t L[64 * 64];
  int s0 = blockIdx.x * 64, d0 = blockIdx.y * 64;
  const uint16_t* src = Vin + (size_t)blockIdx.z * S_ * D_;
  uint16_t* dst = Vt + (size_t)blockIdx.z * S_ * D_;
  int t = threadIdx.x;
  int rr = t >> 3, cb = t & 7;
  #pragma unroll
  for (int half = 0; half < 2; ++half) {
    int row = rr + half * 32;
    uint4 v = *(const uint4*)(src + (size_t)(s0 + row) * D_ + d0 + cb * 8);
    *(uint4*)(L + row * 64 + ((cb ^ (row & 7)) * 8)) = v;
  }
  __syncthreads();
  int dr = t >> 2, sc = (t & 3) * 16;
  union { uint16_t s[16]; uint4 q[2]; } u;
  #pragma unroll
  for (int j = 0; j < 16; ++j) {
    int s = sc + j;
    u.s[j] = L[s * 64 + (((dr >> 3) ^ (s & 7)) * 8) + (dr & 7)];
  }
  uint4* op = (uint4*)(dst + (size_t)(d0 + dr) * S_ + s0 + sc);
  op[0] = u.q[0];
  op[1] = u.q[1];
}

// ------------- GEMM: C = A(MxK,bf16,rm) * Bt(NxK,bf16,rm)^T -------------
// mode 2: f32 rm out; mode 3: fused QKV out -> (b,head,s,d) into Q|K|V slabs
__global__ __launch_bounds__(256) void gemm_bt(const uint16_t* __restrict__ A,
                                               const uint16_t* __restrict__ Bt,
                                               void* __restrict__ Cout,
                                               int M, int N, int K, int mode) {
  __shared__ uint16_t Al[128 * 64];
  __shared__ uint16_t Bl[128 * 64];
  int tid = threadIdx.x;
  int lane = tid & 63, lr = lane & 15, g = lane >> 4;
  int w = tid >> 6, wm = w >> 1, wn = w & 1;
  int wbase = w * 64;
  int m0 = blockIdx.y * 128, n0 = blockIdx.x * 128;
  f32x4 acc[4][4] = {};
  for (int k0 = 0; k0 < K; k0 += 64) {
    __syncthreads();
    #pragma unroll
    for (int p = 0; p < 4; ++p) {
      int c = tid + p * 256;
      int row = c >> 3, cb = c & 7;
      int sc = (cb ^ (row & 7)) * 8;
      gload16(A + (size_t)(m0 + row) * K + k0 + sc, Al + (size_t)(p * 256 + wbase) * 8);
      gload16(Bt + (size_t)(n0 + row) * K + k0 + sc, Bl + (size_t)(p * 256 + wbase) * 8);
    }
    __syncthreads();
    #pragma unroll
    for (int ks = 0; ks < 2; ++ks) {
      bf16x8 af[4], bfr[4];
      #pragma unroll
      for (int mi = 0; mi < 4; ++mi) {
        int row = wm * 64 + mi * 16 + lr;
        af[mi] = *(bf16x8*)((char*)Al + row * 128 + ((ks * 64 + g * 16) ^ ((row & 7) << 4)));
      }
      #pragma unroll
      for (int ni = 0; ni < 4; ++ni) {
        int row = wn * 64 + ni * 16 + lr;
        bfr[ni] = *(bf16x8*)((char*)Bl + row * 128 + ((ks * 64 + g * 16) ^ ((row & 7) << 4)));
      }
      __builtin_amdgcn_s_setprio(1);
      #pragma unroll
      for (int mi = 0; mi < 4; ++mi)
        #pragma unroll
        for (int ni = 0; ni < 4; ++ni)
          acc[mi][ni] = __builtin_amdgcn_mfma_f32_16x16x32_bf16(af[mi], bfr[ni], acc[mi][ni], 0, 0, 0);
      __builtin_amdgcn_s_setprio(0);
    }
  }
  #pragma unroll
  for (int mi = 0; mi < 4; ++mi)
    #pragma unroll
    for (int ni = 0; ni < 4; ++ni)
      #pragma unroll
      for (int e = 0; e < 4; ++e) {
        int row = m0 + wm * 64 + mi * 16 + 4 * g + e;
        int col = n0 + wn * 64 + ni * 16 + lr;
        float v = acc[mi][ni][e];
        if (mode == 2) {
          ((float*)Cout)[(size_t)row * N + col] = v;
        } else {
          int bb = row >> 11, s = row & 2047;
          size_t off;
          if (col < 2048)
            off = (((size_t)(bb * 16 + (col >> 7))) * 2048 + s) * 128 + (col & 127);
          else if (col < 3072)
            off = QSZ_ + (((size_t)(bb * 8 + ((col - 2048) >> 7))) * 2048 + s) * 128 + (col & 127);
          else
            off = QSZ_ + KSZ_ + (((size_t)(bb * 8 + ((col - 3072) >> 7))) * 2048 + s) * 128 + (col & 127);
          ((uint16_t*)Cout)[off] = f2b(v);
        }
      }
}

// ------------- RMSNorm + RoPE (Q pre-scaled by 1/sqrt(D)) -------------
__global__ void norm_rope(uint16_t* __restrict__ Qb, uint16_t* __restrict__ Kb,
                          const float* __restrict__ qw, const float* __restrict__ kw,
                          const float* __restrict__ cosr, const float* __restrict__ sinr) {
  int row = blockIdx.x * 4 + (threadIdx.x >> 6);
  int lane = threadIdx.x & 63;
  int hh = row % 24;
  int bs = row / 24;
  int b = bs >> 11, s = bs & 2047;
  uint16_t* ptr;
  const float* wv;
  float sc;
  if (hh < H_) { ptr = Qb + (((size_t)(b * H_ + hh)) * S_ + s) * D_; wv = qw; sc = SCALE_; }
  else         { ptr = Kb + (((size_t)(b * HKV_ + (hh - H_))) * S_ + s) * D_; wv = kw; sc = 1.0f; }
  float x1 = b2f(ptr[lane]), x2 = b2f(ptr[lane + 64]);
  float ss = x1 * x1 + x2 * x2;
  #pragma unroll
  for (int msk = 1; msk < 64; msk <<= 1) ss += __shfl_xor(ss, msk, 64);
  float r = rsqrtf(ss * (1.0f / 128.0f) + EPS_);
  float n1 = x1 * r * wv[lane], n2 = x2 * r * wv[lane + 64];
  float c1 = cosr[s * 128 + lane], s1 = sinr[s * 128 + lane];
  float c2 = cosr[s * 128 + lane + 64], s2 = sinr[s * 128 + lane + 64];
  ptr[lane]      = f2b((n1 * c1 - n2 * s1) * sc);
  ptr[lane + 64] = f2b((n2 * c2 + n1 * s2) * sc);
}

// ------------- causal GQA flash attention, 32x32 MFMA, KVBLK=64 -------------
// Split-half pipeline: one max/rescale over 64 keys, then
// {exp0,pa0} -> PV0 -> {exp1,pa1} -> PV1 so half1's VALU overlaps PV0's MFMA.
// Diagonal block: even q-tiles skip the (fully masked) upper half entirely.
#define STAGE(BUF, KB) {                                                       \
  int kb64 = (KB) * 64;                                                        \
  _Pragma("unroll") for (int p2 = 0; p2 < 4; ++p2) {                           \
    int ck = p2 * 4 + w;                                                       \
    int krow = ck * 4 + (lane >> 4);                                           \
    int kg = (lane & 15) ^ (krow & 7);                                         \
    gload16(Kg + (size_t)(kb64 + krow) * D_ + kg * 8, Kl[BUF] + ck * 512);     \
    int vrow = ck * 8 + (lane >> 3);                                           \
    int vg = (lane & 7) ^ (vrow & 7);                                          \
    gload16(Vg + (size_t)vrow * S_ + kb64 + vg * 8, Vl[BUF] + ck * 512);       \
  } }

__global__ __launch_bounds__(256, 2) void attn_kernel(const uint16_t* __restrict__ Qb,
                                                      const uint16_t* __restrict__ Kb,
                                                      const uint16_t* __restrict__ Vtg,
                                                      uint16_t* __restrict__ out) {
  __shared__ uint16_t Kl[2][64 * 128];
  __shared__ uint16_t Vl[2][128 * 64];
  int tid = threadIdx.x, lane = tid & 63, w = tid >> 6;
  int ql = lane & 31, hi = lane >> 5;
  int bi = blockIdx.x;
  int qg = 15 - (bi >> 5);            // longest q-groups first
  int rem = bi & 31;
  int bkv = rem >> 1, hsel = rem & 1;
  int b = bkv >> 3, kv = bkv & 7, h = kv * 2 + hsel;
  int qt = qg * 4 + w;
  int q0 = qt * 32;
  int mykb = qt >> 1;                 // last KV block this wave computes
  int kbmax = 2 * qg + 1;             // last KV block any wave in block computes
  const uint16_t* Qg = Qb + ((size_t)(b * H_ + h)) * S_ * D_;
  const uint16_t* Kg = Kb + ((size_t)(b * HKV_ + kv)) * S_ * D_;
  const uint16_t* Vg = Vtg + ((size_t)(b * HKV_ + kv)) * S_ * D_;  // [128][2048]
  bf16x8 qf[8];
  #pragma unroll
  for (int t = 0; t < 8; ++t)
    qf[t] = *(const bf16x8*)(Qg + (size_t)(q0 + ql) * D_ + t * 16 + 8 * hi);
  f32x16 O[4] = {};
  float mrun = -__builtin_inff();
  float lrun = 0.f;
  STAGE(0, 0)
  for (int kb = 0; kb <= kbmax; ++kb) {
    int cur = kb & 1;
    __syncthreads();                  // implicit vmcnt(0): buf[cur] staged; all waves synced
    if (kb < kbmax) STAGE(cur ^ 1, kb + 1)
    if (kb <= mykb) {
      const uint16_t* KlC = Kl[cur];
      const uint16_t* VlC = Vl[cur];
      bool diag = (kb == mykb);
      bool skip2 = diag && ((qt & 1) == 0);   // upper half fully masked
      // ---- QK^T both halves ----
      float p0[16], p1[16];
      {
        bf16x8 kf[8];
        #pragma unroll
        for (int t = 0; t < 8; ++t)
          kf[t] = *(const bf16x8*)(KlC + ql * 128 + (((2 * t + hi) ^ (ql & 7)) * 8));
        f32x16 acc = {};
        __builtin_amdgcn_s_setprio(1);
        #pragma unroll
        for (int t = 0; t < 8; ++t)
          acc = __builtin_amdgcn_mfma_f32_32x32x16_bf16(kf[t], qf[t], acc, 0, 0, 0);
        __builtin_amdgcn_s_setprio(0);
        #pragma unroll
        for (int r = 0; r < 16; ++r) p0[r] = acc[r];
      }
      if (!skip2) {
        bf16x8 kf[8];
        #pragma unroll
        for (int t = 0; t < 8; ++t)
          kf[t] = *(const bf16x8*)(KlC + (32 + ql) * 128 + (((2 * t + hi) ^ (ql & 7)) * 8));
        f32x16 acc = {};
        __builtin_amdgcn_s_setprio(1);
        #pragma unroll
        for (int t = 0; t < 8; ++t)
          acc = __builtin_amdgcn_mfma_f32_32x32x16_bf16(kf[t], qf[t], acc, 0, 0, 0);
        __builtin_amdgcn_s_setprio(0);
        #pragma unroll
        for (int r = 0; r < 16; ++r) p1[r] = acc[r];
      }
      // ---- causal mask (one half only on the diagonal) ----
      if (diag && !(qt & 1)) {
        #pragma unroll
        for (int r = 0; r < 16; ++r) {
          int kk = kb * 64 + 8 * (r >> 2) + 4 * hi + (r & 3);
          if (kk > q0 + ql) p0[r] = -__builtin_inff();
        }
      }
      if (diag && (qt & 1)) {
        #pragma unroll
        for (int r = 0; r < 16; ++r) {
          int kk = kb * 64 + 32 + 8 * (r >> 2) + 4 * hi + (r & 3);
          if (kk > q0 + ql) p1[r] = -__builtin_inff();
        }
      }
      // ---- one max/rescale over all live keys ----
      float m8[8];
      #pragma unroll
      for (int i = 0; i < 8; ++i) m8[i] = fmaxf(p0[i], p0[i + 8]);
      if (!skip2) {
        #pragma unroll
        for (int i = 0; i < 8; ++i) m8[i] = fmaxf(m8[i], fmaxf(p1[i], p1[i + 8]));
      }
      float m4a = fmaxf(m8[0], m8[4]), m4b = fmaxf(m8[1], m8[5]);
      float m4c = fmaxf(m8[2], m8[6]), m4d = fmaxf(m8[3], m8[7]);
      float pmax = fmaxf(fmaxf(m4a, m4b), fmaxf(m4c, m4d));
      pmax = fmaxf(pmax, __shfl_xor(pmax, 32, 64));
      if (__any(pmax > mrun + 8.f)) {
        float mnew = fmaxf(mrun, pmax);
        float rs = __expf(mrun - mnew);
        lrun *= rs;
        #pragma unroll
        for (int r = 0; r < 16; ++r) {
          float rr = __shfl(rs, (r & 3) + 8 * (r >> 2) + 4 * hi, 64);
          #pragma unroll
          for (int dt = 0; dt < 4; ++dt) O[dt][r] *= rr;
        }
        mrun = mnew;
      }
      float ls = 0.f;
      // ---- half0: exp + pack + PV ----
      union PW { uint32_t w[4]; bf16x8 v; } pa0, pa1;
      #pragma unroll
      for (int r = 0; r < 16; ++r) { p0[r] = __expf(p0[r] - mrun); ls += p0[r]; }
      {
        uint32_t uu[4][2];
        #pragma unroll
        for (int T = 0; T < 4; ++T) {
          asm("v_cvt_pk_bf16_f32 %0, %1, %2" : "=v"(uu[T][0]) : "v"(p0[4 * T]), "v"(p0[4 * T + 1]));
          asm("v_cvt_pk_bf16_f32 %0, %1, %2" : "=v"(uu[T][1]) : "v"(p0[4 * T + 2]), "v"(p0[4 * T + 3]));
        }
        uint32_t a = uu[0][0], bb2 = uu[1][0];
        asm("v_permlane32_swap_b32 %0, %1" : "+v"(a), "+v"(bb2));
        uint32_t c = uu[0][1], d = uu[1][1];
        asm("v_permlane32_swap_b32 %0, %1" : "+v"(c), "+v"(d));
        pa0.w[0] = a; pa0.w[1] = c; pa0.w[2] = bb2; pa0.w[3] = d;
        uint32_t a2 = uu[2][0], b2 = uu[3][0];
        asm("v_permlane32_swap_b32 %0, %1" : "+v"(a2), "+v"(b2));
        uint32_t c2 = uu[2][1], d2 = uu[3][1];
        asm("v_permlane32_swap_b32 %0, %1" : "+v"(c2), "+v"(d2));
        pa1.w[0] = a2; pa1.w[1] = c2; pa1.w[2] = b2; pa1.w[3] = d2;
      }
      __builtin_amdgcn_s_setprio(1);
      #pragma unroll
      for (int dt = 0; dt < 4; ++dt) {
        bf16x8 v0 = *(const bf16x8*)(VlC + (dt * 32 + ql) * 64 + (((0 + hi) ^ (ql & 7)) * 8));
        bf16x8 v1 = *(const bf16x8*)(VlC + (dt * 32 + ql) * 64 + (((2 + hi) ^ (ql & 7)) * 8));
        O[dt] = __builtin_amdgcn_mfma_f32_32x32x16_bf16(pa0.v, v0, O[dt], 0, 0, 0);
        O[dt] = __builtin_amdgcn_mfma_f32_32x32x16_bf16(pa1.v, v1, O[dt], 0, 0, 0);
      }
      __builtin_amdgcn_s_setprio(0);
      // ---- half1: exp + pack (overlaps PV0) + PV ----
      if (!skip2) {
        union PW pa2, pa3;
        #pragma unroll
        for (int r = 0; r < 16; ++r) { p1[r] = __expf(p1[r] - mrun); ls += p1[r]; }
        {
          uint32_t uu[4][2];
          #pragma unroll
          for (int T = 0; T < 4; ++T) {
            asm("v_cvt_pk_bf16_f32 %0, %1, %2" : "=v"(uu[T][0]) : "v"(p1[4 * T]), "v"(p1[4 * T + 1]));
            asm("v_cvt_pk_bf16_f32 %0, %1, %2" : "=v"(uu[T][1]) : "v"(p1[4 * T + 2]), "v"(p1[4 * T + 3]));
          }
          uint32_t a = uu[0][0], bb2 = uu[1][0];
          asm("v_permlane32_swap_b32 %0, %1" : "+v"(a), "+v"(bb2));
          uint32_t c = uu[0][1], d = uu[1][1];
          asm("v_permlane32_swap_b32 %0, %1" : "+v"(c), "+v"(d));
          pa2.w[0] = a; pa2.w[1] = c; pa2.w[2] = bb2; pa2.w[3] = d;
          uint32_t a2 = uu[2][0], b2 = uu[3][0];
          asm("v_permlane32_swap_b32 %0, %1" : "+v"(a2), "+v"(b2));
          uint32_t c2 = uu[2][1], d2 = uu[3][1];
          asm("v_permlane32_swap_b32 %0, %1" : "+v"(c2), "+v"(d2));
          pa3.w[0] = a2; pa3.w[1] = c2; pa3.w[2] = b2; pa3.w[3] = d2;
        }
        __builtin_amdgcn_s_setprio(1);
        #pragma unroll
        for (int dt = 0; dt < 4; ++dt) {
          bf16x8 v2 = *(const bf16x8*)(VlC + (dt * 32 + ql) * 64 + (((4 + hi) ^ (ql & 7)) * 8));
          bf16x8 v3 = *(const bf16x8*)(VlC + (dt * 32 + ql) * 64 + (((6 + hi) ^ (ql & 7)) * 8));
          O[dt] = __builtin_amdgcn_mfma_f32_32x32x16_bf16(pa2.v, v2, O[dt], 0, 0, 0);
          O[dt] = __builtin_amdgcn_mfma_f32_32x32x16_bf16(pa3.v, v3, O[dt], 0, 0, 0);
        }
        __builtin_amdgcn_s_setprio(0);
      }
      ls += __shfl_xor(ls, 32, 64);
      lrun += ls;
    }
  }
  float linv = 1.0f / lrun;
  #pragma unroll
  for (int r = 0; r < 16; ++r) {
    int qrl = (r & 3) + 8 * (r >> 2) + 4 * hi;
    float lr_ = __shfl(linv, qrl, 64);
    #pragma unroll
    for (int dt = 0; dt < 4; ++dt) {
      size_t o = ((size_t)(b * S_ + q0 + qrl)) * 2048 + h * 128 + dt * 32 + ql;
      out[o] = f2b(O[dt][r] * lr_);
    }
  }
}

extern "C" void kernel_launch(void* const* d_in, const int* in_sizes, int n_in,
                              void* d_out, int out_size, void* d_ws, size_t ws_size,
                              hipStream_t stream) {
  const float* hidden = (const float*)d_in[0];
  const float* cosr = (const float*)d_in[2];
  const float* sinr = (const float*)d_in[3];
  const float* Wq = (const float*)d_in[4];
  const float* Wk = (const float*)d_in[5];
  const float* Wv = (const float*)d_in[6];
  const float* Wo = (const float*)d_in[7];
  const float* qw = (const float*)d_in[8];
  const float* kw = (const float*)d_in[9];

  uint16_t* p = (uint16_t*)d_ws;
  uint16_t* Xb   = p; p += (size_t)4096 * 1024;
  uint16_t* Wqt  = p; p += (size_t)2048 * 1024;   // Wqt|Wkt|Wvt contiguous = fused 4096x1024 B^T
  uint16_t* Wkt  = p; p += (size_t)1024 * 1024;
  uint16_t* Wvt  = p; p += (size_t)1024 * 1024;
  uint16_t* Wot  = p; p += (size_t)1024 * 2048;
  uint16_t* Qbuf = p; p += (size_t)B_ * H_ * S_ * D_;   // Q|K|V contiguous
  uint16_t* Kbuf = p; p += (size_t)B_ * HKV_ * S_ * D_;
  uint16_t* Vbuf = p; p += (size_t)B_ * HKV_ * S_ * D_;
  uint16_t* attn = p; p += (size_t)4096 * 2048;
  uint16_t* Vtb  = Xb;  // aliases Xb (dead by vtrans time)

  castk<<<4096, 256, 0, stream>>>(hidden, Xb);
  transcast<<<dim3(64, 32), 256, 0, stream>>>(Wq, Wqt, 1024, 2048);
  transcast<<<dim3(32, 32), 256, 0, stream>>>(Wk, Wkt, 1024, 1024);
  transcast<<<dim3(32, 32), 256, 0, stream>>>(Wv, Wvt, 1024, 1024);
  transcast<<<dim3(32, 64), 256, 0, stream>>>(Wo, Wot, 2048, 1024);
  gemm_bt<<<dim3(32, 32), 256, 0, stream>>>(Xb, Wqt, Qbuf, 4096, 4096, 1024, 3);
  vtrans<<<dim3(32, 2, 16), 256, 0, stream>>>(Vbuf, Vtb);
  norm_rope<<<24576, 256, 0, stream>>>(Qbuf, Kbuf, qw, kw, cosr, sinr);
  attn_kernel<<<512, 256, 0, stream>>>(Qbuf, Kbuf, Vtb, attn);
  gemm_bt<<<dim3(8, 32), 256, 0, stream>>>(attn, Wot, d_out, 4096, 1024, 2048, 2);
}

// Round 7
// 194.535 us; speedup vs baseline: 1.8162x; 1.0520x over previous
//
#include <hip/hip_runtime.h>
#include <stdint.h>

#define B_ 2
#define S_ 2048
#define H_ 16
#define HKV_ 8
#define D_ 128
#define EPS_ 1e-6f
#define SCALE_ 0.08838834764831845f
#define QSZ_ 8388608     // B*H*S*D
#define KSZ_ 4194304     // B*HKV*S*D

typedef __attribute__((ext_vector_type(8))) __bf16 bf16x8;
typedef __attribute__((ext_vector_type(4))) float f32x4;
typedef __attribute__((ext_vector_type(16))) float f32x16;

static __device__ __forceinline__ uint16_t f2b(float f) {
  uint32_t u = __builtin_bit_cast(uint32_t, f);
  u += 0x7fffu + ((u >> 16) & 1u);
  return (uint16_t)(u >> 16);
}
static __device__ __forceinline__ float b2f(uint16_t b) {
  uint32_t u = ((uint32_t)b) << 16;
  return __builtin_bit_cast(float, u);
}

typedef const __attribute__((address_space(1))) uint32_t* gas_p;
typedef __attribute__((address_space(3))) uint32_t* las_p;
static __device__ __forceinline__ void gload16(const void* g, void* l) {
  __builtin_amdgcn_global_load_lds((gas_p)g, (las_p)l, 16, 0, 0);
}

// ---------------- cast fp32 -> bf16 (4 elems/thread) ----------------
__global__ void castk(const float* __restrict__ in, uint16_t* __restrict__ out) {
  int i = blockIdx.x * 256 + threadIdx.x;
  float4 f = ((const float4*)in)[i];
  uint2 o;
  o.x = (uint32_t)f2b(f.x) | ((uint32_t)f2b(f.y) << 16);
  o.y = (uint32_t)f2b(f.z) | ((uint32_t)f2b(f.w) << 16);
  ((uint2*)out)[i] = o;
}

// ------------- transpose+cast: W (K x N fp32) -> Wt (N x K bf16) -------------
__global__ void transcast(const float* __restrict__ Wm, uint16_t* __restrict__ Wt,
                          int K, int N) {
  __shared__ float t[32][33];
  int nb = blockIdx.x * 32, kb = blockIdx.y * 32;
  int tx = threadIdx.x & 31, ty = threadIdx.x >> 5;
  #pragma unroll
  for (int i = ty; i < 32; i += 8) t[i][tx] = Wm[(size_t)(kb + i) * N + nb + tx];
  __syncthreads();
  #pragma unroll
  for (int i = ty; i < 32; i += 8) Wt[(size_t)(nb + i) * K + kb + tx] = f2b(t[tx][i]);
}

// ------------- bf16 transpose: V (bkv, s, 128) -> Vt (bkv, 128, s) -------------
__global__ __launch_bounds__(256) void vtrans(const uint16_t* __restrict__ Vin,
                                              uint16_t* __restrict__ Vt) {
  __shared__ uint16_t L[64 * 64];
  int s0 = blockIdx.x * 64, d0 = blockIdx.y * 64;
  const uint16_t* src = Vin + (size_t)blockIdx.z * S_ * D_;
  uint16_t* dst = Vt + (size_t)blockIdx.z * S_ * D_;
  int t = threadIdx.x;
  int rr = t >> 3, cb = t & 7;
  #pragma unroll
  for (int half = 0; half < 2; ++half) {
    int row = rr + half * 32;
    uint4 v = *(const uint4*)(src + (size_t)(s0 + row) * D_ + d0 + cb * 8);
    *(uint4*)(L + row * 64 + ((cb ^ (row & 7)) * 8)) = v;
  }
  __syncthreads();
  int dr = t >> 2, sc = (t & 3) * 16;
  union { uint16_t s[16]; uint4 q[2]; } u;
  #pragma unroll
  for (int j = 0; j < 16; ++j) {
    int s = sc + j;
    u.s[j] = L[s * 64 + (((dr >> 3) ^ (s & 7)) * 8) + (dr & 7)];
  }
  uint4* op = (uint4*)(dst + (size_t)(d0 + dr) * S_ + s0 + sc);
  op[0] = u.q[0];
  op[1] = u.q[1];
}

// ------------- GEMM: C = A(MxK,bf16,rm) * Bt(NxK,bf16,rm)^T -------------
// mode 2: f32 rm out; mode 3: fused QKV out -> (b,head,s,d) into Q|K|V slabs
__global__ __launch_bounds__(256) void gemm_bt(const uint16_t* __restrict__ A,
                                               const uint16_t* __restrict__ Bt,
                                               void* __restrict__ Cout,
                                               int M, int N, int K, int mode) {
  __shared__ uint16_t Al[128 * 64];
  __shared__ uint16_t Bl[128 * 64];
  int tid = threadIdx.x;
  int lane = tid & 63, lr = lane & 15, g = lane >> 4;
  int w = tid >> 6, wm = w >> 1, wn = w & 1;
  int wbase = w * 64;
  int m0 = blockIdx.y * 128, n0 = blockIdx.x * 128;
  f32x4 acc[4][4] = {};
  for (int k0 = 0; k0 < K; k0 += 64) {
    __syncthreads();
    #pragma unroll
    for (int p = 0; p < 4; ++p) {
      int c = tid + p * 256;
      int row = c >> 3, cb = c & 7;
      int sc = (cb ^ (row & 7)) * 8;
      gload16(A + (size_t)(m0 + row) * K + k0 + sc, Al + (size_t)(p * 256 + wbase) * 8);
      gload16(Bt + (size_t)(n0 + row) * K + k0 + sc, Bl + (size_t)(p * 256 + wbase) * 8);
    }
    __syncthreads();
    #pragma unroll
    for (int ks = 0; ks < 2; ++ks) {
      bf16x8 af[4], bfr[4];
      #pragma unroll
      for (int mi = 0; mi < 4; ++mi) {
        int row = wm * 64 + mi * 16 + lr;
        af[mi] = *(bf16x8*)((char*)Al + row * 128 + ((ks * 64 + g * 16) ^ ((row & 7) << 4)));
      }
      #pragma unroll
      for (int ni = 0; ni < 4; ++ni) {
        int row = wn * 64 + ni * 16 + lr;
        bfr[ni] = *(bf16x8*)((char*)Bl + row * 128 + ((ks * 64 + g * 16) ^ ((row & 7) << 4)));
      }
      __builtin_amdgcn_s_setprio(1);
      #pragma unroll
      for (int mi = 0; mi < 4; ++mi)
        #pragma unroll
        for (int ni = 0; ni < 4; ++ni)
          acc[mi][ni] = __builtin_amdgcn_mfma_f32_16x16x32_bf16(af[mi], bfr[ni], acc[mi][ni], 0, 0, 0);
      __builtin_amdgcn_s_setprio(0);
    }
  }
  #pragma unroll
  for (int mi = 0; mi < 4; ++mi)
    #pragma unroll
    for (int ni = 0; ni < 4; ++ni)
      #pragma unroll
      for (int e = 0; e < 4; ++e) {
        int row = m0 + wm * 64 + mi * 16 + 4 * g + e;
        int col = n0 + wn * 64 + ni * 16 + lr;
        float v = acc[mi][ni][e];
        if (mode == 2) {
          ((float*)Cout)[(size_t)row * N + col] = v;
        } else {
          int bb = row >> 11, s = row & 2047;
          size_t off;
          if (col < 2048)
            off = (((size_t)(bb * 16 + (col >> 7))) * 2048 + s) * 128 + (col & 127);
          else if (col < 3072)
            off = QSZ_ + (((size_t)(bb * 8 + ((col - 2048) >> 7))) * 2048 + s) * 128 + (col & 127);
          else
            off = QSZ_ + KSZ_ + (((size_t)(bb * 8 + ((col - 3072) >> 7))) * 2048 + s) * 128 + (col & 127);
          ((uint16_t*)Cout)[off] = f2b(v);
        }
      }
}

// ------------- GEMM variant BM=128, BN=64 (f32 out) — 2x the blocks for small N ---
__global__ __launch_bounds__(256) void gemm_o(const uint16_t* __restrict__ A,
                                              const uint16_t* __restrict__ Bt,
                                              float* __restrict__ Cout,
                                              int M, int N, int K) {
  __shared__ uint16_t Al[128 * 64];
  __shared__ uint16_t Bl[64 * 64];
  int tid = threadIdx.x;
  int lane = tid & 63, lr = lane & 15, g = lane >> 4;
  int w = tid >> 6, wm = w >> 1, wn = w & 1;
  int wbase = w * 64;
  int m0 = blockIdx.y * 128, n0 = blockIdx.x * 64;
  f32x4 acc[4][2] = {};
  for (int k0 = 0; k0 < K; k0 += 64) {
    __syncthreads();
    #pragma unroll
    for (int p = 0; p < 4; ++p) {
      int c = tid + p * 256;
      int row = c >> 3, cb = c & 7;
      int sc = (cb ^ (row & 7)) * 8;
      gload16(A + (size_t)(m0 + row) * K + k0 + sc, Al + (size_t)(p * 256 + wbase) * 8);
    }
    #pragma unroll
    for (int p = 0; p < 2; ++p) {
      int c = tid + p * 256;
      int row = c >> 3, cb = c & 7;
      int sc = (cb ^ (row & 7)) * 8;
      gload16(Bt + (size_t)(n0 + row) * K + k0 + sc, Bl + (size_t)(p * 256 + wbase) * 8);
    }
    __syncthreads();
    #pragma unroll
    for (int ks = 0; ks < 2; ++ks) {
      bf16x8 af[4], bfr[2];
      #pragma unroll
      for (int mi = 0; mi < 4; ++mi) {
        int row = wm * 64 + mi * 16 + lr;
        af[mi] = *(bf16x8*)((char*)Al + row * 128 + ((ks * 64 + g * 16) ^ ((row & 7) << 4)));
      }
      #pragma unroll
      for (int ni = 0; ni < 2; ++ni) {
        int row = wn * 32 + ni * 16 + lr;
        bfr[ni] = *(bf16x8*)((char*)Bl + row * 128 + ((ks * 64 + g * 16) ^ ((row & 7) << 4)));
      }
      __builtin_amdgcn_s_setprio(1);
      #pragma unroll
      for (int mi = 0; mi < 4; ++mi)
        #pragma unroll
        for (int ni = 0; ni < 2; ++ni)
          acc[mi][ni] = __builtin_amdgcn_mfma_f32_16x16x32_bf16(af[mi], bfr[ni], acc[mi][ni], 0, 0, 0);
      __builtin_amdgcn_s_setprio(0);
    }
  }
  #pragma unroll
  for (int mi = 0; mi < 4; ++mi)
    #pragma unroll
    for (int ni = 0; ni < 2; ++ni)
      #pragma unroll
      for (int e = 0; e < 4; ++e) {
        int row = m0 + wm * 64 + mi * 16 + 4 * g + e;
        int col = n0 + wn * 32 + ni * 16 + lr;
        Cout[(size_t)row * N + col] = acc[mi][ni][e];
      }
}

// ------------- RMSNorm + RoPE (Q pre-scaled by 1/sqrt(D)) -------------
__global__ void norm_rope(uint16_t* __restrict__ Qb, uint16_t* __restrict__ Kb,
                          const float* __restrict__ qw, const float* __restrict__ kw,
                          const float* __restrict__ cosr, const float* __restrict__ sinr) {
  int row = blockIdx.x * 4 + (threadIdx.x >> 6);
  int lane = threadIdx.x & 63;
  int hh = row % 24;
  int bs = row / 24;
  int b = bs >> 11, s = bs & 2047;
  uint16_t* ptr;
  const float* wv;
  float sc;
  if (hh < H_) { ptr = Qb + (((size_t)(b * H_ + hh)) * S_ + s) * D_; wv = qw; sc = SCALE_; }
  else         { ptr = Kb + (((size_t)(b * HKV_ + (hh - H_))) * S_ + s) * D_; wv = kw; sc = 1.0f; }
  float x1 = b2f(ptr[lane]), x2 = b2f(ptr[lane + 64]);
  float ss = x1 * x1 + x2 * x2;
  #pragma unroll
  for (int msk = 1; msk < 64; msk <<= 1) ss += __shfl_xor(ss, msk, 64);
  float r = rsqrtf(ss * (1.0f / 128.0f) + EPS_);
  float n1 = x1 * r * wv[lane], n2 = x2 * r * wv[lane + 64];
  float c1 = cosr[s * 128 + lane], s1 = sinr[s * 128 + lane];
  float c2 = cosr[s * 128 + lane + 64], s2 = sinr[s * 128 + lane + 64];
  ptr[lane]      = f2b((n1 * c1 - n2 * s1) * sc);
  ptr[lane + 64] = f2b((n2 * c2 + n1 * s2) * sc);
}

// ------------- causal GQA flash attention, 32x32 MFMA, KVBLK=64 -------------
// Complementary-pair scheduling: blocks bi and bi+256 co-resident on one CU,
// qg mapped so each CU's pair sums to a constant 34 iter-units.
#define STAGE(BUF, KB) {                                                       \
  int kb64 = (KB) * 64;                                                        \
  _Pragma("unroll") for (int p2 = 0; p2 < 4; ++p2) {                           \
    int ck = p2 * 4 + w;                                                       \
    int krow = ck * 4 + (lane >> 4);                                           \
    int kg = (lane & 15) ^ (krow & 7);                                         \
    gload16(Kg + (size_t)(kb64 + krow) * D_ + kg * 8, Kl[BUF] + ck * 512);     \
    int vrow = ck * 8 + (lane >> 3);                                           \
    int vg = (lane & 7) ^ (vrow & 7);                                          \
    gload16(Vg + (size_t)vrow * S_ + kb64 + vg * 8, Vl[BUF] + ck * 512);       \
  } }

__global__ __launch_bounds__(256, 2) void attn_kernel(const uint16_t* __restrict__ Qb,
                                                      const uint16_t* __restrict__ Kb,
                                                      const uint16_t* __restrict__ Vtg,
                                                      uint16_t* __restrict__ out) {
  __shared__ uint16_t Kl[2][64 * 128];
  __shared__ uint16_t Vl[2][128 * 64];
  int tid = threadIdx.x, lane = tid & 63, w = tid >> 6;
  int ql = lane & 31, hi = lane >> 5;
  int bi = blockIdx.x;
  int biH = bi >> 8;                  // 0 = long half, 1 = short half
  int j = bi & 255;
  int qgl = j >> 5;                   // 0..7
  int qg = biH ? qgl : 15 - qgl;      // pair (bi, bi+256) sums to 34 iter-units
  int rem = j & 31;
  int bkv = rem >> 1, hsel = rem & 1;
  int b = bkv >> 3, kv = bkv & 7, h = kv * 2 + hsel;
  int qt = qg * 4 + w;
  int q0 = qt * 32;
  int mykb = qt >> 1;                 // last KV block this wave computes
  int kbmax = 2 * qg + 1;             // last KV block any wave in block computes
  const uint16_t* Qg = Qb + ((size_t)(b * H_ + h)) * S_ * D_;
  const uint16_t* Kg = Kb + ((size_t)(b * HKV_ + kv)) * S_ * D_;
  const uint16_t* Vg = Vtg + ((size_t)(b * HKV_ + kv)) * S_ * D_;  // [128][2048]
  bf16x8 qf[8];
  #pragma unroll
  for (int t = 0; t < 8; ++t)
    qf[t] = *(const bf16x8*)(Qg + (size_t)(q0 + ql) * D_ + t * 16 + 8 * hi);
  f32x16 O[4] = {};
  float mrun = -__builtin_inff();
  float lrun = 0.f;
  STAGE(0, 0)
  for (int kb = 0; kb <= kbmax; ++kb) {
    int cur = kb & 1;
    __syncthreads();                  // implicit vmcnt(0): buf[cur] staged; all waves synced
    if (kb < kbmax) STAGE(cur ^ 1, kb + 1)
    if (kb <= mykb) {
      const uint16_t* KlC = Kl[cur];
      const uint16_t* VlC = Vl[cur];
      bool diag = (kb == mykb);
      bool skip2 = diag && ((qt & 1) == 0);   // upper half fully masked
      // ---- QK^T both halves ----
      float p0[16], p1[16];
      {
        bf16x8 kf[8];
        #pragma unroll
        for (int t = 0; t < 8; ++t)
          kf[t] = *(const bf16x8*)(KlC + ql * 128 + (((2 * t + hi) ^ (ql & 7)) * 8));
        f32x16 acc = {};
        __builtin_amdgcn_s_setprio(1);
        #pragma unroll
        for (int t = 0; t < 8; ++t)
          acc = __builtin_amdgcn_mfma_f32_32x32x16_bf16(kf[t], qf[t], acc, 0, 0, 0);
        __builtin_amdgcn_s_setprio(0);
        #pragma unroll
        for (int r = 0; r < 16; ++r) p0[r] = acc[r];
      }
      if (!skip2) {
        bf16x8 kf[8];
        #pragma unroll
        for (int t = 0; t < 8; ++t)
          kf[t] = *(const bf16x8*)(KlC + (32 + ql) * 128 + (((2 * t + hi) ^ (ql & 7)) * 8));
        f32x16 acc = {};
        __builtin_amdgcn_s_setprio(1);
        #pragma unroll
        for (int t = 0; t < 8; ++t)
          acc = __builtin_amdgcn_mfma_f32_32x32x16_bf16(kf[t], qf[t], acc, 0, 0, 0);
        __builtin_amdgcn_s_setprio(0);
        #pragma unroll
        for (int r = 0; r < 16; ++r) p1[r] = acc[r];
      }
      // ---- causal mask (one half only on the diagonal) ----
      if (diag && !(qt & 1)) {
        #pragma unroll
        for (int r = 0; r < 16; ++r) {
          int kk = kb * 64 + 8 * (r >> 2) + 4 * hi + (r & 3);
          if (kk > q0 + ql) p0[r] = -__builtin_inff();
        }
      }
      if (diag && (qt & 1)) {
        #pragma unroll
        for (int r = 0; r < 16; ++r) {
          int kk = kb * 64 + 32 + 8 * (r >> 2) + 4 * hi + (r & 3);
          if (kk > q0 + ql) p1[r] = -__builtin_inff();
        }
      }
      // ---- one max/rescale over all live keys ----
      float m8[8];
      #pragma unroll
      for (int i = 0; i < 8; ++i) m8[i] = fmaxf(p0[i], p0[i + 8]);
      if (!skip2) {
        #pragma unroll
        for (int i = 0; i < 8; ++i) m8[i] = fmaxf(m8[i], fmaxf(p1[i], p1[i + 8]));
      }
      float m4a = fmaxf(m8[0], m8[4]), m4b = fmaxf(m8[1], m8[5]);
      float m4c = fmaxf(m8[2], m8[6]), m4d = fmaxf(m8[3], m8[7]);
      float pmax = fmaxf(fmaxf(m4a, m4b), fmaxf(m4c, m4d));
      pmax = fmaxf(pmax, __shfl_xor(pmax, 32, 64));
      if (__any(pmax > mrun + 8.f)) {
        float mnew = fmaxf(mrun, pmax);
        float rs = __expf(mrun - mnew);
        lrun *= rs;
        #pragma unroll
        for (int r = 0; r < 16; ++r) {
          float rr = __shfl(rs, (r & 3) + 8 * (r >> 2) + 4 * hi, 64);
          #pragma unroll
          for (int dt = 0; dt < 4; ++dt) O[dt][r] *= rr;
        }
        mrun = mnew;
      }
      float ls = 0.f;
      // ---- half0: exp + pack + PV ----
      union PW { uint32_t w[4]; bf16x8 v; } pa0, pa1;
      #pragma unroll
      for (int r = 0; r < 16; ++r) { p0[r] = __expf(p0[r] - mrun); ls += p0[r]; }
      {
        uint32_t uu[4][2];
        #pragma unroll
        for (int T = 0; T < 4; ++T) {
          asm("v_cvt_pk_bf16_f32 %0, %1, %2" : "=v"(uu[T][0]) : "v"(p0[4 * T]), "v"(p0[4 * T + 1]));
          asm("v_cvt_pk_bf16_f32 %0, %1, %2" : "=v"(uu[T][1]) : "v"(p0[4 * T + 2]), "v"(p0[4 * T + 3]));
        }
        uint32_t a = uu[0][0], bb2 = uu[1][0];
        asm("v_permlane32_swap_b32 %0, %1" : "+v"(a), "+v"(bb2));
        uint32_t c = uu[0][1], d = uu[1][1];
        asm("v_permlane32_swap_b32 %0, %1" : "+v"(c), "+v"(d));
        pa0.w[0] = a; pa0.w[1] = c; pa0.w[2] = bb2; pa0.w[3] = d;
        uint32_t a2 = uu[2][0], b2 = uu[3][0];
        asm("v_permlane32_swap_b32 %0, %1" : "+v"(a2), "+v"(b2));
        uint32_t c2 = uu[2][1], d2 = uu[3][1];
        asm("v_permlane32_swap_b32 %0, %1" : "+v"(c2), "+v"(d2));
        pa1.w[0] = a2; pa1.w[1] = c2; pa1.w[2] = b2; pa1.w[3] = d2;
      }
      __builtin_amdgcn_s_setprio(1);
      #pragma unroll
      for (int dt = 0; dt < 4; ++dt) {
        bf16x8 v0 = *(const bf16x8*)(VlC + (dt * 32 + ql) * 64 + (((0 + hi) ^ (ql & 7)) * 8));
        bf16x8 v1 = *(const bf16x8*)(VlC + (dt * 32 + ql) * 64 + (((2 + hi) ^ (ql & 7)) * 8));
        O[dt] = __builtin_amdgcn_mfma_f32_32x32x16_bf16(pa0.v, v0, O[dt], 0, 0, 0);
        O[dt] = __builtin_amdgcn_mfma_f32_32x32x16_bf16(pa1.v, v1, O[dt], 0, 0, 0);
      }
      __builtin_amdgcn_s_setprio(0);
      // ---- half1: exp + pack (overlaps PV0) + PV ----
      if (!skip2) {
        union PW pa2, pa3;
        #pragma unroll
        for (int r = 0; r < 16; ++r) { p1[r] = __expf(p1[r] - mrun); ls += p1[r]; }
        {
          uint32_t uu[4][2];
          #pragma unroll
          for (int T = 0; T < 4; ++T) {
            asm("v_cvt_pk_bf16_f32 %0, %1, %2" : "=v"(uu[T][0]) : "v"(p1[4 * T]), "v"(p1[4 * T + 1]));
            asm("v_cvt_pk_bf16_f32 %0, %1, %2" : "=v"(uu[T][1]) : "v"(p1[4 * T + 2]), "v"(p1[4 * T + 3]));
          }
          uint32_t a = uu[0][0], bb2 = uu[1][0];
          asm("v_permlane32_swap_b32 %0, %1" : "+v"(a), "+v"(bb2));
          uint32_t c = uu[0][1], d = uu[1][1];
          asm("v_permlane32_swap_b32 %0, %1" : "+v"(c), "+v"(d));
          pa2.w[0] = a; pa2.w[1] = c; pa2.w[2] = bb2; pa2.w[3] = d;
          uint32_t a2 = uu[2][0], b2 = uu[3][0];
          asm("v_permlane32_swap_b32 %0, %1" : "+v"(a2), "+v"(b2));
          uint32_t c2 = uu[2][1], d2 = uu[3][1];
          asm("v_permlane32_swap_b32 %0, %1" : "+v"(c2), "+v"(d2));
          pa3.w[0] = a2; pa3.w[1] = c2; pa3.w[2] = b2; pa3.w[3] = d2;
        }
        __builtin_amdgcn_s_setprio(1);
        #pragma unroll
        for (int dt = 0; dt < 4; ++dt) {
          bf16x8 v2 = *(const bf16x8*)(VlC + (dt * 32 + ql) * 64 + (((4 + hi) ^ (ql & 7)) * 8));
          bf16x8 v3 = *(const bf16x8*)(VlC + (dt * 32 + ql) * 64 + (((6 + hi) ^ (ql & 7)) * 8));
          O[dt] = __builtin_amdgcn_mfma_f32_32x32x16_bf16(pa2.v, v2, O[dt], 0, 0, 0);
          O[dt] = __builtin_amdgcn_mfma_f32_32x32x16_bf16(pa3.v, v3, O[dt], 0, 0, 0);
        }
        __builtin_amdgcn_s_setprio(0);
      }
      ls += __shfl_xor(ls, 32, 64);
      lrun += ls;
    }
  }
  float linv = 1.0f / lrun;
  #pragma unroll
  for (int r = 0; r < 16; ++r) {
    int qrl = (r & 3) + 8 * (r >> 2) + 4 * hi;
    float lr_ = __shfl(linv, qrl, 64);
    #pragma unroll
    for (int dt = 0; dt < 4; ++dt) {
      size_t o = ((size_t)(b * S_ + q0 + qrl)) * 2048 + h * 128 + dt * 32 + ql;
      out[o] = f2b(O[dt][r] * lr_);
    }
  }
}

extern "C" void kernel_launch(void* const* d_in, const int* in_sizes, int n_in,
                              void* d_out, int out_size, void* d_ws, size_t ws_size,
                              hipStream_t stream) {
  const float* hidden = (const float*)d_in[0];
  const float* cosr = (const float*)d_in[2];
  const float* sinr = (const float*)d_in[3];
  const float* Wq = (const float*)d_in[4];
  const float* Wk = (const float*)d_in[5];
  const float* Wv = (const float*)d_in[6];
  const float* Wo = (const float*)d_in[7];
  const float* qw = (const float*)d_in[8];
  const float* kw = (const float*)d_in[9];

  uint16_t* p = (uint16_t*)d_ws;
  uint16_t* Xb   = p; p += (size_t)4096 * 1024;
  uint16_t* Wqt  = p; p += (size_t)2048 * 1024;   // Wqt|Wkt|Wvt contiguous = fused 4096x1024 B^T
  uint16_t* Wkt  = p; p += (size_t)1024 * 1024;
  uint16_t* Wvt  = p; p += (size_t)1024 * 1024;
  uint16_t* Wot  = p; p += (size_t)1024 * 2048;
  uint16_t* Qbuf = p; p += (size_t)B_ * H_ * S_ * D_;   // Q|K|V contiguous
  uint16_t* Kbuf = p; p += (size_t)B_ * HKV_ * S_ * D_;
  uint16_t* Vbuf = p; p += (size_t)B_ * HKV_ * S_ * D_;
  uint16_t* attn = p; p += (size_t)4096 * 2048;
  uint16_t* Vtb  = Xb;  // aliases Xb (dead by vtrans time)

  castk<<<4096, 256, 0, stream>>>(hidden, Xb);
  transcast<<<dim3(64, 32), 256, 0, stream>>>(Wq, Wqt, 1024, 2048);
  transcast<<<dim3(32, 32), 256, 0, stream>>>(Wk, Wkt, 1024, 1024);
  transcast<<<dim3(32, 32), 256, 0, stream>>>(Wv, Wvt, 1024, 1024);
  transcast<<<dim3(32, 64), 256, 0, stream>>>(Wo, Wot, 2048, 1024);
  gemm_bt<<<dim3(32, 32), 256, 0, stream>>>(Xb, Wqt, Qbuf, 4096, 4096, 1024, 3);
  vtrans<<<dim3(32, 2, 16), 256, 0, stream>>>(Vbuf, Vtb);
  norm_rope<<<24576, 256, 0, stream>>>(Qbuf, Kbuf, qw, kw, cosr, sinr);
  attn_kernel<<<512, 256, 0, stream>>>(Qbuf, Kbuf, Vtb, attn);
  gemm_o<<<dim3(16, 32), 256, 0, stream>>>(attn, Wot, (float*)d_out, 4096, 1024, 2048);
}

// Round 8
// 174.916 us; speedup vs baseline: 2.0199x; 1.1122x over previous
//
#include <hip/hip_runtime.h>
#include <stdint.h>

#define B_ 2
#define S_ 2048
#define H_ 16
#define HKV_ 8
#define D_ 128
#define EPS_ 1e-6f
#define SCALE_ 0.08838834764831845f

typedef __attribute__((ext_vector_type(8))) __bf16 bf16x8;
typedef __attribute__((ext_vector_type(4))) float f32x4;
typedef __attribute__((ext_vector_type(16))) float f32x16;

static __device__ __forceinline__ uint16_t f2b(float f) {
  uint32_t u = __builtin_bit_cast(uint32_t, f);
  u += 0x7fffu + ((u >> 16) & 1u);
  return (uint16_t)(u >> 16);
}
static __device__ __forceinline__ float b2f(uint16_t b) {
  uint32_t u = ((uint32_t)b) << 16;
  return __builtin_bit_cast(float, u);
}

typedef const __attribute__((address_space(1))) uint32_t* gas_p;
typedef __attribute__((address_space(3))) uint32_t* las_p;
static __device__ __forceinline__ void gload16(const void* g, void* l) {
  __builtin_amdgcn_global_load_lds((gas_p)g, (las_p)l, 16, 0, 0);
}

// ------------- prep: castk (blocks 0..4095) + 4 weight transposes -------------
__global__ __launch_bounds__(256) void prep(const float* __restrict__ hidden,
                                            uint16_t* __restrict__ Xb,
                                            const float* __restrict__ Wq,
                                            const float* __restrict__ Wk,
                                            const float* __restrict__ Wv,
                                            const float* __restrict__ Wo,
                                            uint16_t* __restrict__ Wqt,
                                            uint16_t* __restrict__ Wkt,
                                            uint16_t* __restrict__ Wvt,
                                            uint16_t* __restrict__ Wot) {
  __shared__ float tt[32][33];
  int bid = blockIdx.x;
  if (bid < 4096) {   // cast hidden fp32 -> bf16
    int i = bid * 256 + threadIdx.x;
    float4 f = ((const float4*)hidden)[i];
    uint2 o;
    o.x = (uint32_t)f2b(f.x) | ((uint32_t)f2b(f.y) << 16);
    o.y = (uint32_t)f2b(f.z) | ((uint32_t)f2b(f.w) << 16);
    ((uint2*)Xb)[i] = o;
    return;
  }
  bid -= 4096;
  const float* src; uint16_t* dst; int K, N, bx, by;
  if (bid < 2048)       { src = Wq; dst = Wqt; K = 1024; N = 2048; bx = bid & 63; by = bid >> 6; }
  else if (bid < 3072)  { bid -= 2048; src = Wk; dst = Wkt; K = 1024; N = 1024; bx = bid & 31; by = bid >> 5; }
  else if (bid < 4096)  { bid -= 3072; src = Wv; dst = Wvt; K = 1024; N = 1024; bx = bid & 31; by = bid >> 5; }
  else                  { bid -= 4096; src = Wo; dst = Wot; K = 2048; N = 1024; bx = bid & 31; by = bid >> 5; }
  int nb = bx * 32, kb = by * 32;
  int tx = threadIdx.x & 31, ty = threadIdx.x >> 5;
  #pragma unroll
  for (int i = ty; i < 32; i += 8) tt[i][tx] = src[(size_t)(kb + i) * N + nb + tx];
  __syncthreads();
  #pragma unroll
  for (int i = ty; i < 32; i += 8) dst[(size_t)(nb + i) * K + kb + tx] = f2b(tt[tx][i]);
}

// ------------- fused QKV GEMM: X(4096x1024) * Wqkv^T(4096x1024)^T -------------
// Epilogue per 128-col block = one head: Q/K -> RMSNorm+RoPE(+SCALE for Q) in
// place; V -> transposed store into Vt[bkv][d][s]. LDS staging reused as the
// epilogue exchange tile (same 32KB).
__global__ __launch_bounds__(256) void gemm_qkv(const uint16_t* __restrict__ A,
                                                const uint16_t* __restrict__ Bt,
                                                uint16_t* __restrict__ Qb,
                                                uint16_t* __restrict__ Kb,
                                                uint16_t* __restrict__ Vtb,
                                                const float* __restrict__ qw,
                                                const float* __restrict__ kw,
                                                const float* __restrict__ cosr,
                                                const float* __restrict__ sinr) {
  __shared__ uint16_t Sh[128 * 128];   // staging (Al|Bl) and epilogue tile alias
  uint16_t* Al = Sh;
  uint16_t* Bl = Sh + 128 * 64;
  int tid = threadIdx.x;
  int lane = tid & 63, lr = lane & 15, g = lane >> 4;
  int w = tid >> 6, wm = w >> 1, wn = w & 1;
  int wbase = w * 64;
  int m0 = blockIdx.y * 128, n0 = blockIdx.x * 128;
  f32x4 acc[4][4] = {};
  for (int k0 = 0; k0 < 1024; k0 += 64) {
    __syncthreads();
    #pragma unroll
    for (int p = 0; p < 4; ++p) {
      int c = tid + p * 256;
      int row = c >> 3, cb = c & 7;
      int sc = (cb ^ (row & 7)) * 8;
      gload16(A + (size_t)(m0 + row) * 1024 + k0 + sc, Al + (size_t)(p * 256 + wbase) * 8);
      gload16(Bt + (size_t)(n0 + row) * 1024 + k0 + sc, Bl + (size_t)(p * 256 + wbase) * 8);
    }
    __syncthreads();
    #pragma unroll
    for (int ks = 0; ks < 2; ++ks) {
      bf16x8 af[4], bfr[4];
      #pragma unroll
      for (int mi = 0; mi < 4; ++mi) {
        int row = wm * 64 + mi * 16 + lr;
        af[mi] = *(bf16x8*)((char*)Al + row * 128 + ((ks * 64 + g * 16) ^ ((row & 7) << 4)));
      }
      #pragma unroll
      for (int ni = 0; ni < 4; ++ni) {
        int row = wn * 64 + ni * 16 + lr;
        bfr[ni] = *(bf16x8*)((char*)Bl + row * 128 + ((ks * 64 + g * 16) ^ ((row & 7) << 4)));
      }
      __builtin_amdgcn_s_setprio(1);
      #pragma unroll
      for (int mi = 0; mi < 4; ++mi)
        #pragma unroll
        for (int ni = 0; ni < 4; ++ni)
          acc[mi][ni] = __builtin_amdgcn_mfma_f32_16x16x32_bf16(af[mi], bfr[ni], acc[mi][ni], 0, 0, 0);
      __builtin_amdgcn_s_setprio(0);
    }
  }
  // ---- epilogue: acc -> swizzled LDS bf16 [128 rows][128 cols] ----
  __syncthreads();
  uint16_t* L = Sh;
  #pragma unroll
  for (int mi = 0; mi < 4; ++mi)
    #pragma unroll
    for (int ni = 0; ni < 4; ++ni)
      #pragma unroll
      for (int e = 0; e < 4; ++e) {
        int row = wm * 64 + mi * 16 + 4 * g + e;
        int col = wn * 64 + ni * 16 + lr;
        L[row * 128 + ((((col >> 3) ^ (row & 7)) << 3) | (col & 7))] = f2b(acc[mi][ni][e]);
      }
  __syncthreads();
  int hsel = n0 >> 7;   // 0..15 Q-head, 16..23 K-head, 24..31 V-head
  if (hsel < 24) {
    // RMSNorm + RoPE: 2 threads per row, each owns cols {d0..d0+31, d0+64..d0+95}
    int row = tid >> 1, half = tid & 1;
    int gr = m0 + row, bb = gr >> 11, s = gr & 2047;
    int d0 = half * 32;
    float x[64];
    #pragma unroll
    for (int c8 = 0; c8 < 8; ++c8) {
      int j = (c8 & 3) * 8 + d0 + (c8 >> 2) * 64;
      union { bf16x8 v; uint16_t u[8]; } tmp;
      tmp.v = *(bf16x8*)(L + row * 128 + (((j >> 3) ^ (row & 7)) << 3));
      #pragma unroll
      for (int k = 0; k < 8; ++k) x[c8 * 8 + k] = b2f(tmp.u[k]);
    }
    float ss = 0.f;
    #pragma unroll
    for (int k = 0; k < 64; ++k) ss += x[k] * x[k];
    ss += __shfl_xor(ss, 1, 64);
    float rn = rsqrtf(ss * (1.0f / 128.0f) + EPS_);
    const float* wv = (hsel < 16) ? qw : kw;
    float scq = (hsel < 16) ? SCALE_ : 1.0f;
    rn *= scq;
    uint16_t* outp = (hsel < 16)
      ? Qb + (((size_t)(bb * 16 + hsel)) * 2048 + s) * 128
      : Kb + (((size_t)(bb * 8 + (hsel - 16))) * 2048 + s) * 128;
    const float* cR = cosr + s * 128;
    const float* sR = sinr + s * 128;
    #pragma unroll
    for (int c = 0; c < 4; ++c) {
      int dlo = d0 + c * 8;
      uint16_t olo[8], ohi[8];
      #pragma unroll
      for (int k = 0; k < 8; ++k) {
        int d = dlo + k;
        float x1 = x[c * 8 + k] * rn * wv[d];
        float x2 = x[32 + c * 8 + k] * rn * wv[d + 64];
        olo[k] = f2b(x1 * cR[d] - x2 * sR[d]);
        ohi[k] = f2b(x2 * cR[d + 64] + x1 * sR[d + 64]);
      }
      *(uint4*)(outp + dlo) = *(uint4*)olo;
      *(uint4*)(outp + 64 + dlo) = *(uint4*)ohi;
    }
  } else {
    // V: transposed store -> Vt[(b*8+kv)][d][s]
    int kvh = hsel - 24;
    int d0 = tid >> 1, sh = tid & 1;
    int bb = m0 >> 11, sg0 = (m0 & 2047) + sh * 64;
    union { uint16_t u[64]; uint4 q[8]; } vv;
    #pragma unroll
    for (int sl = 0; sl < 64; ++sl) {
      int srow = sh * 64 + sl;
      vv.u[sl] = L[srow * 128 + ((((d0 >> 3) ^ (srow & 7)) << 3) | (d0 & 7))];
    }
    uint16_t* vt = Vtb + (((size_t)(bb * 8 + kvh)) * 128 + d0) * 2048 + sg0;
    #pragma unroll
    for (int c = 0; c < 8; ++c) *(uint4*)(vt + c * 8) = vv.q[c];
  }
}

// ------------- GEMM BM=128, BN=64 (f32 out) for the O-projection -------------
__global__ __launch_bounds__(256) void gemm_o(const uint16_t* __restrict__ A,
                                              const uint16_t* __restrict__ Bt,
                                              float* __restrict__ Cout,
                                              int M, int N, int K) {
  __shared__ uint16_t Al[128 * 64];
  __shared__ uint16_t Bl[64 * 64];
  int tid = threadIdx.x;
  int lane = tid & 63, lr = lane & 15, g = lane >> 4;
  int w = tid >> 6, wm = w >> 1, wn = w & 1;
  int wbase = w * 64;
  int m0 = blockIdx.y * 128, n0 = blockIdx.x * 64;
  f32x4 acc[4][2] = {};
  for (int k0 = 0; k0 < K; k0 += 64) {
    __syncthreads();
    #pragma unroll
    for (int p = 0; p < 4; ++p) {
      int c = tid + p * 256;
      int row = c >> 3, cb = c & 7;
      int sc = (cb ^ (row & 7)) * 8;
      gload16(A + (size_t)(m0 + row) * K + k0 + sc, Al + (size_t)(p * 256 + wbase) * 8);
    }
    #pragma unroll
    for (int p = 0; p < 2; ++p) {
      int c = tid + p * 256;
      int row = c >> 3, cb = c & 7;
      int sc = (cb ^ (row & 7)) * 8;
      gload16(Bt + (size_t)(n0 + row) * K + k0 + sc, Bl + (size_t)(p * 256 + wbase) * 8);
    }
    __syncthreads();
    #pragma unroll
    for (int ks = 0; ks < 2; ++ks) {
      bf16x8 af[4], bfr[2];
      #pragma unroll
      for (int mi = 0; mi < 4; ++mi) {
        int row = wm * 64 + mi * 16 + lr;
        af[mi] = *(bf16x8*)((char*)Al + row * 128 + ((ks * 64 + g * 16) ^ ((row & 7) << 4)));
      }
      #pragma unroll
      for (int ni = 0; ni < 2; ++ni) {
        int row = wn * 32 + ni * 16 + lr;
        bfr[ni] = *(bf16x8*)((char*)Bl + row * 128 + ((ks * 64 + g * 16) ^ ((row & 7) << 4)));
      }
      __builtin_amdgcn_s_setprio(1);
      #pragma unroll
      for (int mi = 0; mi < 4; ++mi)
        #pragma unroll
        for (int ni = 0; ni < 2; ++ni)
          acc[mi][ni] = __builtin_amdgcn_mfma_f32_16x16x32_bf16(af[mi], bfr[ni], acc[mi][ni], 0, 0, 0);
      __builtin_amdgcn_s_setprio(0);
    }
  }
  #pragma unroll
  for (int mi = 0; mi < 4; ++mi)
    #pragma unroll
    for (int ni = 0; ni < 2; ++ni)
      #pragma unroll
      for (int e = 0; e < 4; ++e) {
        int row = m0 + wm * 64 + mi * 16 + 4 * g + e;
        int col = n0 + wn * 32 + ni * 16 + lr;
        Cout[(size_t)row * N + col] = acc[mi][ni][e];
      }
}

// ------------- causal GQA flash attention, 32x32 MFMA, KVBLK=64 -------------
#define STAGE(BUF, KB) {                                                       \
  int kb64 = (KB) * 64;                                                        \
  _Pragma("unroll") for (int p2 = 0; p2 < 4; ++p2) {                           \
    int ck = p2 * 4 + w;                                                       \
    int krow = ck * 4 + (lane >> 4);                                           \
    int kg = (lane & 15) ^ (krow & 7);                                         \
    gload16(Kg + (size_t)(kb64 + krow) * D_ + kg * 8, Kl[BUF] + ck * 512);     \
    int vrow = ck * 8 + (lane >> 3);                                           \
    int vg = (lane & 7) ^ (vrow & 7);                                          \
    gload16(Vg + (size_t)vrow * S_ + kb64 + vg * 8, Vl[BUF] + ck * 512);       \
  } }

__global__ __launch_bounds__(256, 2) void attn_kernel(const uint16_t* __restrict__ Qb,
                                                      const uint16_t* __restrict__ Kb,
                                                      const uint16_t* __restrict__ Vtg,
                                                      uint16_t* __restrict__ out) {
  __shared__ uint16_t Kl[2][64 * 128];
  __shared__ uint16_t Vl[2][128 * 64];
  int tid = threadIdx.x, lane = tid & 63, w = tid >> 6;
  int ql = lane & 31, hi = lane >> 5;
  int bi = blockIdx.x;
  int biH = bi >> 8;
  int j = bi & 255;
  int qgl = j >> 5;
  int qg = biH ? qgl : 15 - qgl;
  int rem = j & 31;
  int bkv = rem >> 1, hsel = rem & 1;
  int b = bkv >> 3, kv = bkv & 7, h = kv * 2 + hsel;
  int qt = qg * 4 + w;
  int q0 = qt * 32;
  int mykb = qt >> 1;
  int kbmax = 2 * qg + 1;
  const uint16_t* Qg = Qb + ((size_t)(b * H_ + h)) * S_ * D_;
  const uint16_t* Kg = Kb + ((size_t)(b * HKV_ + kv)) * S_ * D_;
  const uint16_t* Vg = Vtg + ((size_t)(b * HKV_ + kv)) * S_ * D_;  // [128][2048]
  bf16x8 qf[8];
  #pragma unroll
  for (int t = 0; t < 8; ++t)
    qf[t] = *(const bf16x8*)(Qg + (size_t)(q0 + ql) * D_ + t * 16 + 8 * hi);
  f32x16 O[4] = {};
  float mrun = -__builtin_inff();
  float lrun = 0.f;
  STAGE(0, 0)
  for (int kb = 0; kb <= kbmax; ++kb) {
    int cur = kb & 1;
    __syncthreads();
    if (kb < kbmax) STAGE(cur ^ 1, kb + 1)
    if (kb <= mykb) {
      const uint16_t* KlC = Kl[cur];
      const uint16_t* VlC = Vl[cur];
      bool diag = (kb == mykb);
      bool skip2 = diag && ((qt & 1) == 0);
      float p0[16], p1[16];
      {
        bf16x8 kf[8];
        #pragma unroll
        for (int t = 0; t < 8; ++t)
          kf[t] = *(const bf16x8*)(KlC + ql * 128 + (((2 * t + hi) ^ (ql & 7)) * 8));
        f32x16 acc = {};
        __builtin_amdgcn_s_setprio(1);
        #pragma unroll
        for (int t = 0; t < 8; ++t)
          acc = __builtin_amdgcn_mfma_f32_32x32x16_bf16(kf[t], qf[t], acc, 0, 0, 0);
        __builtin_amdgcn_s_setprio(0);
        #pragma unroll
        for (int r = 0; r < 16; ++r) p0[r] = acc[r];
      }
      if (!skip2) {
        bf16x8 kf[8];
        #pragma unroll
        for (int t = 0; t < 8; ++t)
          kf[t] = *(const bf16x8*)(KlC + (32 + ql) * 128 + (((2 * t + hi) ^ (ql & 7)) * 8));
        f32x16 acc = {};
        __builtin_amdgcn_s_setprio(1);
        #pragma unroll
        for (int t = 0; t < 8; ++t)
          acc = __builtin_amdgcn_mfma_f32_32x32x16_bf16(kf[t], qf[t], acc, 0, 0, 0);
        __builtin_amdgcn_s_setprio(0);
        #pragma unroll
        for (int r = 0; r < 16; ++r) p1[r] = acc[r];
      }
      if (diag && !(qt & 1)) {
        #pragma unroll
        for (int r = 0; r < 16; ++r) {
          int kk = kb * 64 + 8 * (r >> 2) + 4 * hi + (r & 3);
          if (kk > q0 + ql) p0[r] = -__builtin_inff();
        }
      }
      if (diag && (qt & 1)) {
        #pragma unroll
        for (int r = 0; r < 16; ++r) {
          int kk = kb * 64 + 32 + 8 * (r >> 2) + 4 * hi + (r & 3);
          if (kk > q0 + ql) p1[r] = -__builtin_inff();
        }
      }
      float m8[8];
      #pragma unroll
      for (int i = 0; i < 8; ++i) m8[i] = fmaxf(p0[i], p0[i + 8]);
      if (!skip2) {
        #pragma unroll
        for (int i = 0; i < 8; ++i) m8[i] = fmaxf(m8[i], fmaxf(p1[i], p1[i + 8]));
      }
      float m4a = fmaxf(m8[0], m8[4]), m4b = fmaxf(m8[1], m8[5]);
      float m4c = fmaxf(m8[2], m8[6]), m4d = fmaxf(m8[3], m8[7]);
      float pmax = fmaxf(fmaxf(m4a, m4b), fmaxf(m4c, m4d));
      pmax = fmaxf(pmax, __shfl_xor(pmax, 32, 64));
      if (__any(pmax > mrun + 8.f)) {
        float mnew = fmaxf(mrun, pmax);
        float rs = __expf(mrun - mnew);
        lrun *= rs;
        #pragma unroll
        for (int r = 0; r < 16; ++r) {
          float rr = __shfl(rs, (r & 3) + 8 * (r >> 2) + 4 * hi, 64);
          #pragma unroll
          for (int dt = 0; dt < 4; ++dt) O[dt][r] *= rr;
        }
        mrun = mnew;
      }
      float ls = 0.f;
      union PW { uint32_t w[4]; bf16x8 v; } pa0, pa1;
      #pragma unroll
      for (int r = 0; r < 16; ++r) { p0[r] = __expf(p0[r] - mrun); ls += p0[r]; }
      {
        uint32_t uu[4][2];
        #pragma unroll
        for (int T = 0; T < 4; ++T) {
          asm("v_cvt_pk_bf16_f32 %0, %1, %2" : "=v"(uu[T][0]) : "v"(p0[4 * T]), "v"(p0[4 * T + 1]));
          asm("v_cvt_pk_bf16_f32 %0, %1, %2" : "=v"(uu[T][1]) : "v"(p0[4 * T + 2]), "v"(p0[4 * T + 3]));
        }
        uint32_t a = uu[0][0], bb2 = uu[1][0];
        asm("v_permlane32_swap_b32 %0, %1" : "+v"(a), "+v"(bb2));
        uint32_t c = uu[0][1], d = uu[1][1];
        asm("v_permlane32_swap_b32 %0, %1" : "+v"(c), "+v"(d));
        pa0.w[0] = a; pa0.w[1] = c; pa0.w[2] = bb2; pa0.w[3] = d;
        uint32_t a2 = uu[2][0], b2 = uu[3][0];
        asm("v_permlane32_swap_b32 %0, %1" : "+v"(a2), "+v"(b2));
        uint32_t c2 = uu[2][1], d2 = uu[3][1];
        asm("v_permlane32_swap_b32 %0, %1" : "+v"(c2), "+v"(d2));
        pa1.w[0] = a2; pa1.w[1] = c2; pa1.w[2] = b2; pa1.w[3] = d2;
      }
      __builtin_amdgcn_s_setprio(1);
      #pragma unroll
      for (int dt = 0; dt < 4; ++dt) {
        bf16x8 v0 = *(const bf16x8*)(VlC + (dt * 32 + ql) * 64 + (((0 + hi) ^ (ql & 7)) * 8));
        bf16x8 v1 = *(const bf16x8*)(VlC + (dt * 32 + ql) * 64 + (((2 + hi) ^ (ql & 7)) * 8));
        O[dt] = __builtin_amdgcn_mfma_f32_32x32x16_bf16(pa0.v, v0, O[dt], 0, 0, 0);
        O[dt] = __builtin_amdgcn_mfma_f32_32x32x16_bf16(pa1.v, v1, O[dt], 0, 0, 0);
      }
      __builtin_amdgcn_s_setprio(0);
      if (!skip2) {
        union PW pa2, pa3;
        #pragma unroll
        for (int r = 0; r < 16; ++r) { p1[r] = __expf(p1[r] - mrun); ls += p1[r]; }
        {
          uint32_t uu[4][2];
          #pragma unroll
          for (int T = 0; T < 4; ++T) {
            asm("v_cvt_pk_bf16_f32 %0, %1, %2" : "=v"(uu[T][0]) : "v"(p1[4 * T]), "v"(p1[4 * T + 1]));
            asm("v_cvt_pk_bf16_f32 %0, %1, %2" : "=v"(uu[T][1]) : "v"(p1[4 * T + 2]), "v"(p1[4 * T + 3]));
          }
          uint32_t a = uu[0][0], bb2 = uu[1][0];
          asm("v_permlane32_swap_b32 %0, %1" : "+v"(a), "+v"(bb2));
          uint32_t c = uu[0][1], d = uu[1][1];
          asm("v_permlane32_swap_b32 %0, %1" : "+v"(c), "+v"(d));
          pa2.w[0] = a; pa2.w[1] = c; pa2.w[2] = bb2; pa2.w[3] = d;
          uint32_t a2 = uu[2][0], b2 = uu[3][0];
          asm("v_permlane32_swap_b32 %0, %1" : "+v"(a2), "+v"(b2));
          uint32_t c2 = uu[2][1], d2 = uu[3][1];
          asm("v_permlane32_swap_b32 %0, %1" : "+v"(c2), "+v"(d2));
          pa3.w[0] = a2; pa3.w[1] = c2; pa3.w[2] = b2; pa3.w[3] = d2;
        }
        __builtin_amdgcn_s_setprio(1);
        #pragma unroll
        for (int dt = 0; dt < 4; ++dt) {
          bf16x8 v2 = *(const bf16x8*)(VlC + (dt * 32 + ql) * 64 + (((4 + hi) ^ (ql & 7)) * 8));
          bf16x8 v3 = *(const bf16x8*)(VlC + (dt * 32 + ql) * 64 + (((6 + hi) ^ (ql & 7)) * 8));
          O[dt] = __builtin_amdgcn_mfma_f32_32x32x16_bf16(pa2.v, v2, O[dt], 0, 0, 0);
          O[dt] = __builtin_amdgcn_mfma_f32_32x32x16_bf16(pa3.v, v3, O[dt], 0, 0, 0);
        }
        __builtin_amdgcn_s_setprio(0);
      }
      ls += __shfl_xor(ls, 32, 64);
      lrun += ls;
    }
  }
  float linv = 1.0f / lrun;
  #pragma unroll
  for (int r = 0; r < 16; ++r) {
    int qrl = (r & 3) + 8 * (r >> 2) + 4 * hi;
    float lr_ = __shfl(linv, qrl, 64);
    #pragma unroll
    for (int dt = 0; dt < 4; ++dt) {
      size_t o = ((size_t)(b * S_ + q0 + qrl)) * 2048 + h * 128 + dt * 32 + ql;
      out[o] = f2b(O[dt][r] * lr_);
    }
  }
}

extern "C" void kernel_launch(void* const* d_in, const int* in_sizes, int n_in,
                              void* d_out, int out_size, void* d_ws, size_t ws_size,
                              hipStream_t stream) {
  const float* hidden = (const float*)d_in[0];
  const float* cosr = (const float*)d_in[2];
  const float* sinr = (const float*)d_in[3];
  const float* Wq = (const float*)d_in[4];
  const float* Wk = (const float*)d_in[5];
  const float* Wv = (const float*)d_in[6];
  const float* Wo = (const float*)d_in[7];
  const float* qw = (const float*)d_in[8];
  const float* kw = (const float*)d_in[9];

  uint16_t* p = (uint16_t*)d_ws;
  uint16_t* Xb   = p; p += (size_t)4096 * 1024;
  uint16_t* Wqt  = p; p += (size_t)2048 * 1024;   // Wqt|Wkt|Wvt contiguous = fused 4096x1024 B^T
  uint16_t* Wkt  = p; p += (size_t)1024 * 1024;
  uint16_t* Wvt  = p; p += (size_t)1024 * 1024;
  uint16_t* Wot  = p; p += (size_t)1024 * 2048;
  uint16_t* Qbuf = p; p += (size_t)B_ * H_ * S_ * D_;
  uint16_t* Kbuf = p; p += (size_t)B_ * HKV_ * S_ * D_;
  uint16_t* Vtb  = p; p += (size_t)B_ * HKV_ * S_ * D_;   // V^T [bkv][128][2048]
  uint16_t* attn = p; p += (size_t)4096 * 2048;

  prep<<<10240, 256, 0, stream>>>(hidden, Xb, Wq, Wk, Wv, Wo, Wqt, Wkt, Wvt, Wot);
  gemm_qkv<<<dim3(32, 32), 256, 0, stream>>>(Xb, Wqt, Qbuf, Kbuf, Vtb, qw, kw, cosr, sinr);
  attn_kernel<<<512, 256, 0, stream>>>(Qbuf, Kbuf, Vtb, attn);
  gemm_o<<<dim3(16, 32), 256, 0, stream>>>(attn, Wot, (float*)d_out, 4096, 1024, 2048);
}